// Round 9
// baseline (488.539 us; speedup 1.0000x reference)
//
#include <hip/hip_runtime.h>
#include <hip/hip_bf16.h>

#define LSEQ 4096
#define BSZ 2
#define DMODEL 512
#define DINNER 1024
#define DSTATE 64
#define NHEADS 16
#define CONVDIM 1152
#define DPROJ 2192
#define NPAD 2304
#define NTOK (BSZ*LSEQ)
#define NCH 64   /* 64-token chunks */

typedef __attribute__((ext_vector_type(8))) short short8;
typedef __attribute__((ext_vector_type(4))) float f32x4;

__device__ inline unsigned short f2b(float v){
  unsigned int u = __builtin_bit_cast(unsigned int, v);
  unsigned int r = (u + 0x7FFFu + ((u >> 16) & 1u)) >> 16;
  return (unsigned short)r;
}
__device__ inline float b2f(unsigned short u){
  unsigned int x = ((unsigned int)u) << 16;
  return __builtin_bit_cast(float, x);
}
__device__ inline uint4 pack8(const float* v){
  uint4 pk;
  pk.x = (unsigned)f2b(v[0]) | ((unsigned)f2b(v[1])<<16);
  pk.y = (unsigned)f2b(v[2]) | ((unsigned)f2b(v[3])<<16);
  pk.z = (unsigned)f2b(v[4]) | ((unsigned)f2b(v[5])<<16);
  pk.w = (unsigned)f2b(v[6]) | ((unsigned)f2b(v[7])<<16);
  return pk;
}

#define GLL16(gp, lp) __builtin_amdgcn_global_load_lds( \
    (const __attribute__((address_space(1))) unsigned int*)(gp), \
    (__attribute__((address_space(3))) unsigned int*)(lp), 16, 0, 0)

// ---------------- weight transpose + f32->bf16 (src [K][Nsrc] -> dst [Npad][K]) ----
__global__ __launch_bounds__(256) void wconv_t(const float* __restrict__ src,
    unsigned short* __restrict__ dst, int K, int Nsrc, int Npad){
  __shared__ float t[32][33];
  int n0 = blockIdx.x*32, k0 = blockIdx.y*32;
  int tx = threadIdx.x & 31, ty = threadIdx.x >> 5;
  for (int i=0;i<4;i++){
    int k = k0 + ty + i*8; int n = n0 + tx;
    t[ty + i*8][tx] = (n < Nsrc) ? src[(size_t)k*Nsrc + n] : 0.f;
  }
  __syncthreads();
  for (int i=0;i<4;i++){
    int n = n0 + ty + i*8; int k = k0 + tx;
    if (n < Npad) dst[(size_t)n*K + k] = f2b(t[tx][ty + i*8]);
  }
}

// ---------------- layernorm over 512 cols (f32 in) -> bf16 ----------------
__global__ __launch_bounds__(256) void layernorm_k(const float* __restrict__ in,
    const float* __restrict__ w, const float* __restrict__ bb, unsigned short* __restrict__ out){
  int row = blockIdx.x; int tid = threadIdx.x;
  const float* r = in + (size_t)row*DMODEL;
  float v0 = r[tid], v1 = r[tid+256];
  float s = v0+v1, sq = v0*v0+v1*v1;
  for (int m=32;m>=1;m>>=1){ s += __shfl_xor(s,m); sq += __shfl_xor(sq,m); }
  __shared__ float ws_[4], wq_[4];
  int wave = tid>>6, lane = tid&63;
  if (lane==0){ ws_[wave]=s; wq_[wave]=sq; }
  __syncthreads();
  s = ws_[0]+ws_[1]+ws_[2]+ws_[3]; sq = wq_[0]+wq_[1]+wq_[2]+wq_[3];
  float mu = s * (1.f/DMODEL);
  float var = sq * (1.f/DMODEL) - mu*mu;
  float rs = rsqrtf(var + 1e-5f);
  out[(size_t)row*DMODEL + tid]     = f2b((v0-mu)*rs*w[tid] + bb[tid]);
  out[(size_t)row*DMODEL + tid+256] = f2b((v1-mu)*rs*w[tid+256] + bb[tid+256]);
}

// ---------------- bf16 MFMA GEMM: C[M,N] = A[M,K] @ Bt[N,K]^T ----------------
// Double-buffered async staging (global_load_lds w16): one barrier per K-iter,
// next tile's DMA overlaps current tile's ds_read+MFMA. TN = 128 or 64.
// epi 0: f32 plain ; 1: bf16 gelu(v+bias) ; 2: f32 v+bias+resid ; 3: bf16 plain
template<int TN>
__global__ __launch_bounds__(256) void gemm_k(const unsigned short* __restrict__ A,
    const unsigned short* __restrict__ Bt, void* __restrict__ outp,
    int M, int N, int K, int epi, const float* __restrict__ bias, const float* __restrict__ resid){
  constexpr int NT  = TN/32;               // n-tiles per wave
  constexpr int BUF = 128*32 + TN*32;      // shorts per buffer
  __shared__ __align__(16) unsigned short smem[2*BUF];
  int tid = threadIdx.x;
  int lane = tid & 63, wave = tid >> 6;
  int wr = wave >> 1, wc = wave & 1;
  int l15 = lane & 15, q = lane >> 4;
  int bm = blockIdx.y, bn = blockIdx.x;
  f32x4 acc[4][NT];
  for (int i=0;i<4;i++) for(int j=0;j<NT;j++) acc[i][j] = (f32x4){0.f,0.f,0.f,0.f};
  const size_t abase = (size_t)bm*128*K;
  const size_t bbase = (size_t)bn*TN*K;
  auto stage = [&](int pb, int k0){
    unsigned short* As = smem + pb*BUF;
    unsigned short* Bs = As + 128*32;
    #pragma unroll
    for (int i=0;i<2;i++){
      int idx = tid + i*256; int rr = idx>>2, cg = idx&3;
      GLL16(A + abase + (size_t)rr*K + k0 + cg*8, As + idx*8);
    }
    #pragma unroll
    for (int i=0;i<TN/64;i++){
      int idx = tid + i*256; int rr = idx>>2, cg = idx&3;
      GLL16(Bt + bbase + (size_t)rr*K + k0 + cg*8, Bs + idx*8);
    }
  };
  int nk = K >> 5;
  stage(0, 0);
  for (int it=0; it<nk; ++it){
    int cur = it & 1;
    __syncthreads();                       // drain: buf[cur] ready
    if (it+1 < nk) stage(cur^1, (it+1)<<5); // async prefetch overlaps compute below
    const unsigned short* As = smem + cur*BUF;
    const unsigned short* Bs = As + 128*32;
    short8 af[4], bfr[NT];
    #pragma unroll
    for (int mt=0;mt<4;mt++) af[mt]  = *(const short8*)(&As[(wr*64+mt*16+l15)*32 + q*8]);
    #pragma unroll
    for (int nt=0;nt<NT;nt++) bfr[nt] = *(const short8*)(&Bs[(wc*(TN/2)+nt*16+l15)*32 + q*8]);
    #pragma unroll
    for (int mt=0;mt<4;mt++)
      #pragma unroll
      for (int nt=0;nt<NT;nt++)
        acc[mt][nt] = __builtin_amdgcn_mfma_f32_16x16x32_bf16(af[mt], bfr[nt], acc[mt][nt], 0,0,0);
  }
  __syncthreads();                         // all fragment reads done before cbuf overlay
  // ---- coalesced epilogue (per-wave 16-row LDS slab overlaying staging) ----
  constexpr int CW = TN/2 + 1;             // padded f32 row stride
  float* cbuf = ((float*)smem) + wave*(16*CW);
  int rbase = q*4;
  int gr0t = bm*128 + wr*64;
  int gc0 = bn*TN + wc*(TN/2);
  for (int mt=0; mt<4; mt++){
    #pragma unroll
    for (int nt=0;nt<NT;nt++)
      #pragma unroll
      for (int rr=0;rr<4;rr++)
        cbuf[(rbase+rr)*CW + nt*16 + l15] = acc[mt][nt][rr];
    int gr0 = gr0t + mt*16;
    if (epi == 1 || epi == 3){
      constexpr int LPR = TN/16, RPP = 64/LPR, NP = 16/RPP;
      int rr_ = lane / LPR, c0 = (lane % LPR)*8;
      #pragma unroll
      for (int h=0; h<NP; h++){
        int row = h*RPP + rr_;
        float v[8];
        #pragma unroll
        for (int t=0;t<8;t++) v[t] = cbuf[row*CW + c0 + t];
        if (epi == 1){
          #pragma unroll
          for (int t=0;t<8;t++){
            float bv = v[t] + bias[gc0 + c0 + t];
            v[t] = 0.5f*bv*(1.f+erff(bv*0.70710678118654752f));
          }
        }
        *(uint4*)((unsigned short*)outp + (size_t)(gr0+row)*N + gc0 + c0) = pack8(v);
      }
    } else {
      constexpr int LPR = TN/8, RPP = 64/LPR, NP = 16/RPP;
      int rr_ = lane / LPR, c0 = (lane % LPR)*4;
      #pragma unroll
      for (int h=0; h<NP; h++){
        int row = h*RPP + rr_;
        float4 v;
        v.x = cbuf[row*CW + c0 + 0];
        v.y = cbuf[row*CW + c0 + 1];
        v.z = cbuf[row*CW + c0 + 2];
        v.w = cbuf[row*CW + c0 + 3];
        if (epi == 2){
          const float4 rv = *(const float4*)(resid + (size_t)(gr0+row)*N + gc0 + c0);
          v.x += bias[gc0+c0+0] + rv.x;
          v.y += bias[gc0+c0+1] + rv.y;
          v.z += bias[gc0+c0+2] + rv.z;
          v.w += bias[gc0+c0+3] + rv.w;
        }
        *(float4*)((float*)outp + (size_t)(gr0+row)*N + gc0 + c0) = v;
      }
    }
  }
}

// ---------------- dt/dA per (token, head), written for both directions ----------------
__global__ __launch_bounds__(256) void dt_k(const unsigned short* __restrict__ zx,
    const float* __restrict__ dt_bias, const float* __restrict__ A_log,
    float* __restrict__ dAb, float* __restrict__ dtb){
  int b = blockIdx.y;
  int t = blockIdx.x*16 + (threadIdx.x>>4);
  int h = threadIdx.x & 15;
  float raw = b2f(zx[((size_t)b*LSEQ + t)*NPAD + (DINNER+CONVDIM) + h]) + dt_bias[h];
  float dt = (raw > 20.f) ? raw : log1pf(expf(raw));
  float dA = expf(-expf(A_log[h]) * dt);
  size_t f = ((size_t)b*LSEQ + t)*NHEADS + h;
  size_t r = ((size_t)(BSZ+b)*LSEQ + (LSEQ-1-t))*NHEADS + h;
  dAb[f] = dA; dtb[f] = dt;
  dAb[r] = dA; dtb[r] = dt;
}

// ---------------- conv+silu for x-channels, BOTH directions, + z compaction ----------
__global__ __launch_bounds__(256) void conv_x_k(const unsigned short* __restrict__ zx,
    const float* __restrict__ conv_w, const float* __restrict__ conv_b,
    const float* __restrict__ dtb, unsigned short* __restrict__ dtxb,
    unsigned short* __restrict__ zcomp){
  int b = blockIdx.y;
  int t0blk = blockIdx.x * 32;
  int tid = threadIdx.x;
  int half = tid >> 7, cg = tid & 127;
  int c0 = cg * 8;
  int head = c0 >> 6;
  float wk[4][8], bias8[8];
  #pragma unroll
  for (int k=0;k<4;k++)
    #pragma unroll
    for (int j=0;j<8;j++) wk[k][j] = conv_w[k*CONVDIM + c0 + j];
  #pragma unroll
  for (int j=0;j<8;j++) bias8[j] = conv_b[c0 + j];
  __shared__ float sdtf[32][16], sdtb[32][16];
  for (int r = tid; r < 512; r += 256){
    int i = r >> 4, h = r & 15;
    sdtf[i][h] = dtb[((size_t)b*LSEQ + t0blk + i)*NHEADS + h];
    sdtb[i][h] = dtb[((size_t)(BSZ+b)*LSEQ + (LSEQ-1-(t0blk+i)))*NHEADS + h];
  }
  __syncthreads();
  int t0 = t0blk + half*16;
  float w0[8],w1[8],w2[8],w3[8];
  #pragma unroll
  for (int j=0;j<8;j++){ w1[j]=0.f; w2[j]=0.f; w3[j]=0.f; }
  for (int it=0; it<22; ++it){
    int t = t0 - 3 + it;
    #pragma unroll
    for (int j=0;j<8;j++){ w0[j]=w1[j]; w1[j]=w2[j]; w2[j]=w3[j]; }
    if (t >= 0 && t < LSEQ){
      uint4 xv = *(const uint4*)(zx + ((size_t)b*LSEQ + t)*NPAD + DINNER + c0);
      const unsigned short* xs = (const unsigned short*)&xv;
      #pragma unroll
      for (int j=0;j<8;j++) w3[j] = b2f(xs[j]);
      if (t >= t0 && t < t0+16){
        uint4 zv = *(const uint4*)(zx + ((size_t)b*LSEQ + t)*NPAD + c0);
        *(uint4*)(zcomp + ((size_t)b*LSEQ + t)*DINNER + c0) = zv;
      }
    } else {
      #pragma unroll
      for (int j=0;j<8;j++) w3[j] = 0.f;
    }
    if (t >= t0 && t < t0+16){
      float dtf = sdtf[t - t0blk][head];
      float v[8];
      #pragma unroll
      for (int j=0;j<8;j++){
        float a = bias8[j] + wk[0][j]*w0[j] + wk[1][j]*w1[j] + wk[2][j]*w2[j] + wk[3][j]*w3[j];
        v[j] = (a / (1.f + expf(-a))) * dtf;
      }
      *(uint4*)(dtxb + ((size_t)b*LSEQ + t)*DINNER + c0) = pack8(v);
    }
    int tau = t - 3;
    if (tau >= t0 && tau < t0+16){
      float dtv = sdtb[tau - t0blk][head];
      float v[8];
      #pragma unroll
      for (int j=0;j<8;j++){
        float a = bias8[j] + wk[0][j]*w3[j] + wk[1][j]*w2[j] + wk[2][j]*w1[j] + wk[3][j]*w0[j];
        v[j] = (a / (1.f + expf(-a))) * dtv;
      }
      *(uint4*)(dtxb + ((size_t)(BSZ+b)*LSEQ + (LSEQ-1-tau))*DINNER + c0) = pack8(v);
    }
  }
}

// ---------------- conv+silu for B/C channels, both directions ----------------
__global__ __launch_bounds__(256) void conv_bc_k(const unsigned short* __restrict__ zx,
    const float* __restrict__ conv_w, const float* __restrict__ conv_b,
    unsigned short* __restrict__ Bb, unsigned short* __restrict__ Cb){
  int b = blockIdx.y;
  int t0blk = blockIdx.x * 64;
  int tid = threadIdx.x;
  int slot = tid >> 4, cg = tid & 15;
  int c0 = cg*8;
  int ccol = DINNER + 1024 + c0;
  int cw = 1024 + c0;
  float wk[4][8], bias8[8];
  #pragma unroll
  for (int k=0;k<4;k++)
    #pragma unroll
    for (int j=0;j<8;j++) wk[k][j] = conv_w[k*CONVDIM + cw + j];
  #pragma unroll
  for (int j=0;j<8;j++) bias8[j] = conv_b[cw + j];
  int t0 = t0blk + slot*4;
  float w0[8],w1[8],w2[8],w3[8];
  #pragma unroll
  for (int j=0;j<8;j++){ w1[j]=0.f; w2[j]=0.f; w3[j]=0.f; }
  for (int it=0; it<10; ++it){
    int t = t0 - 3 + it;
    #pragma unroll
    for (int j=0;j<8;j++){ w0[j]=w1[j]; w1[j]=w2[j]; w2[j]=w3[j]; }
    if (t >= 0 && t < LSEQ){
      uint4 xv = *(const uint4*)(zx + ((size_t)b*LSEQ + t)*NPAD + ccol);
      const unsigned short* xs = (const unsigned short*)&xv;
      #pragma unroll
      for (int j=0;j<8;j++) w3[j] = b2f(xs[j]);
    } else {
      #pragma unroll
      for (int j=0;j<8;j++) w3[j] = 0.f;
    }
    if (t >= t0 && t < t0+4){
      float v[8];
      #pragma unroll
      for (int j=0;j<8;j++){
        float a = bias8[j] + wk[0][j]*w0[j] + wk[1][j]*w1[j] + wk[2][j]*w2[j] + wk[3][j]*w3[j];
        v[j] = a / (1.f + expf(-a));
      }
      size_t tok = (size_t)b*LSEQ + t;
      if (c0 < 64) *(uint4*)(Bb + tok*DSTATE + c0)      = pack8(v);
      else         *(uint4*)(Cb + tok*DSTATE + (c0-64)) = pack8(v);
    }
    int tau = t - 3;
    if (tau >= t0 && tau < t0+4){
      float v[8];
      #pragma unroll
      for (int j=0;j<8;j++){
        float a = bias8[j] + wk[0][j]*w3[j] + wk[1][j]*w2[j] + wk[2][j]*w1[j] + wk[3][j]*w0[j];
        v[j] = a / (1.f + expf(-a));
      }
      size_t tok = (size_t)(BSZ+b)*LSEQ + (LSEQ-1-tau);
      if (c0 < 64) *(uint4*)(Bb + tok*DSTATE + c0)      = pack8(v);
      else         *(uint4*)(Cb + tok*DSTATE + (c0-64)) = pack8(v);
    }
  }
}

// ---- 64x64x64 bf16 GEMM on one wave: D += A(S-rows m, k contiguous) * B(S-rows n)^T
__device__ inline void gemm64(const unsigned short* Ab, const unsigned short* Bb_,
                              int l15, int q, f32x4 acc[4][4]){
  #pragma unroll
  for (int ks=0; ks<2; ks++){
    short8 af[4], bf4[4];
    #pragma unroll
    for (int mt=0;mt<4;mt++) af[mt]  = *(const short8*)(Ab  + (mt*16+l15)*72 + ks*32 + q*8);
    #pragma unroll
    for (int nt=0;nt<4;nt++) bf4[nt] = *(const short8*)(Bb_ + (nt*16+l15)*72 + ks*32 + q*8);
    #pragma unroll
    for (int mt=0;mt<4;mt++)
      #pragma unroll
      for (int nt=0;nt<4;nt++)
        acc[mt][nt] = __builtin_amdgcn_mfma_f32_16x16x32_bf16(af[mt], bf4[nt], acc[mt][nt], 0,0,0);
  }
}

// ---------------- SSD pass 1: per chunk: Y_intra (masked attention form) + local state G ----
__global__ __launch_bounds__(64) void ssd1_k(const float* __restrict__ dAb,
    const unsigned short* __restrict__ dtxb, const unsigned short* __restrict__ Bb,
    const unsigned short* __restrict__ Cb,
    unsigned short* __restrict__ y0, unsigned short* __restrict__ y1,
    unsigned short* __restrict__ hbuf, float* __restrict__ Pch, float* __restrict__ ebuf){
  int ch = blockIdx.x, h = blockIdx.y, z = blockIdx.z;
  int d = z >> 1, b = z & 1;
  int lane = threadIdx.x;
  int l15 = lane & 15, q = lane >> 4;
  int tr = lane >> 3, cb8 = (lane & 7)*8;
  size_t tokb = (size_t)z*LSEQ + (size_t)ch*64;
  size_t zhc = ((size_t)z*NHEADS + h)*NCH + ch;
  __shared__ __align__(16) unsigned short S1[64*72];
  __shared__ __align__(16) unsigned short S2[64*72];
  __shared__ __align__(16) unsigned short S3[64*72];
  __shared__ float Lb[64];
  float L = fmaxf(logf(dAb[(tokb + lane)*NHEADS + h]), -60.f);
  #pragma unroll
  for (int off=1; off<64; off<<=1){
    float v = __shfl_up(L, off);
    if (lane >= off) L += v;
  }
  Lb[lane] = L;
  float e = expf(L);
  ebuf[zhc*64 + lane] = e;
  if (lane == 63) Pch[zhc] = e;
  for (int i=0;i<8;i++){
    int t = i*8 + tr;
    *(uint4*)&S1[t*72 + cb8] = *(const uint4*)(Cb + (tokb+t)*DSTATE + cb8);
    *(uint4*)&S2[t*72 + cb8] = *(const uint4*)(Bb + (tokb+t)*DSTATE + cb8);
    uint4 xv = *(const uint4*)(dtxb + (tokb+t)*DINNER + (size_t)h*64 + cb8);
    const unsigned short* xs = (const unsigned short*)&xv;
    #pragma unroll
    for (int j=0;j<8;j++) S3[(cb8+j)*72 + t] = xs[j];
  }
  f32x4 sa[4][4];
  for (int i=0;i<4;i++) for (int j=0;j<4;j++) sa[i][j] = (f32x4){0.f,0.f,0.f,0.f};
  gemm64(S1, S2, l15, q, sa);
  float Lsv[4];
  #pragma unroll
  for (int nt=0;nt<4;nt++) Lsv[nt] = Lb[nt*16 + l15];
  #pragma unroll
  for (int mt=0;mt<4;mt++){
    #pragma unroll
    for (int r=0;r<4;r++){
      int t = mt*16 + q*4 + r;
      float Lt = Lb[t];
      #pragma unroll
      for (int nt=0;nt<4;nt++){
        int s = nt*16 + l15;
        float v = (t >= s) ? expf(Lt - Lsv[nt]) * sa[mt][nt][r] : 0.f;
        S1[t*72 + s] = f2b(v);
      }
    }
  }
  f32x4 ya[4][4];
  for (int i=0;i<4;i++) for (int j=0;j<4;j++) ya[i][j] = (f32x4){0.f,0.f,0.f,0.f};
  gemm64(S1, S3, l15, q, ya);
  #pragma unroll
  for (int mt=0;mt<4;mt++)
    #pragma unroll
    for (int pt=0;pt<4;pt++)
      #pragma unroll
      for (int r=0;r<4;r++)
        S2[(mt*16+q*4+r)*72 + pt*16 + l15] = f2b(ya[mt][pt][r]);
  unsigned short* yb = d ? y1 : y0;
  for (int i=0;i<8;i++){
    int t = i*8 + tr; int g = ch*64 + t;
    int tph = d ? (LSEQ-1-g) : g;
    *(uint4*)(yb + ((size_t)b*LSEQ + tph)*DINNER + (size_t)h*64 + cb8) = *(uint4*)&S2[t*72 + cb8];
  }
  float L63 = Lb[63];
  for (int i=0;i<8;i++){
    int s = i*8 + tr;
    float w = expf(L63 - Lb[s]);
    uint4 bv = *(const uint4*)(Bb + (tokb+s)*DSTATE + cb8);
    const unsigned short* bs = (const unsigned short*)&bv;
    #pragma unroll
    for (int j=0;j<8;j++) S2[(cb8+j)*72 + s] = f2b(w * b2f(bs[j]));
  }
  f32x4 ga[4][4];
  for (int i=0;i<4;i++) for (int j=0;j<4;j++) ga[i][j] = (f32x4){0.f,0.f,0.f,0.f};
  gemm64(S3, S2, l15, q, ga);
  #pragma unroll
  for (int pt=0;pt<4;pt++)
    #pragma unroll
    for (int nt=0;nt<4;nt++)
      #pragma unroll
      for (int r=0;r<4;r++)
        S1[(pt*16+q*4+r)*72 + nt*16 + l15] = f2b(ga[pt][nt][r]);
  for (int i=0;i<8;i++){
    int p = i*8 + tr;
    *(uint4*)(hbuf + zhc*4096 + (size_t)p*64 + cb8) = *(uint4*)&S1[p*72 + cb8];
  }
}

// ---------------- combine chunk states, IN PLACE ----------------
__global__ __launch_bounds__(256) void comb_k(unsigned short* __restrict__ hbuf,
    const float* __restrict__ Pch){
  int u = blockIdx.x; int tid = threadIdx.x;
  float hreg[16];
  #pragma unroll
  for (int k=0;k<16;k++) hreg[k]=0.f;
  for (int ch=0; ch<NCH; ch++){
    size_t base = ((size_t)u*NCH + ch)*4096;
    float P = Pch[(size_t)u*NCH + ch];
    #pragma unroll
    for (int k=0;k<16;k++){
      float t = b2f(hbuf[base + tid + k*256]);
      hbuf[base + tid + k*256] = f2b(hreg[k]);
      hreg[k] = hreg[k]*P + t;
    }
  }
}

// ---------------- SSD pass 2: Y += diag(e) C h_in^T + D*xh ----------------
__global__ __launch_bounds__(64) void ssd2_k(const unsigned short* __restrict__ Cb,
    const unsigned short* __restrict__ hbuf, const unsigned short* __restrict__ dtxb,
    const float* __restrict__ dtb, const float* __restrict__ ebuf, const float* __restrict__ Dh,
    unsigned short* __restrict__ y0, unsigned short* __restrict__ y1){
  int ch = blockIdx.x, h = blockIdx.y, z = blockIdx.z;
  int d = z >> 1, b = z & 1;
  int lane = threadIdx.x;
  int l15 = lane & 15, q = lane >> 4;
  int tr = lane >> 3, cb8 = (lane & 7)*8;
  size_t tokb = (size_t)z*LSEQ + (size_t)ch*64;
  size_t zhc = ((size_t)z*NHEADS + h)*NCH + ch;
  __shared__ __align__(16) unsigned short S1[64*72];
  __shared__ __align__(16) unsigned short S2[64*72];
  __shared__ __align__(16) unsigned short S3[64*72];
  __shared__ float eb2[64], dti[64];
  eb2[lane] = ebuf[zhc*64 + lane];
  dti[lane] = 1.f / dtb[(tokb + lane)*NHEADS + h];
  float Dv = Dh[h];
  for (int i=0;i<8;i++){
    int t = i*8 + tr;
    *(uint4*)&S1[t*72 + cb8] = *(const uint4*)(Cb + (tokb+t)*DSTATE + cb8);
    *(uint4*)&S2[t*72 + cb8] = *(const uint4*)(hbuf + zhc*4096 + (size_t)t*64 + cb8);
  }
  f32x4 acc[4][4];
  for (int i=0;i<4;i++) for (int j=0;j<4;j++) acc[i][j] = (f32x4){0.f,0.f,0.f,0.f};
  gemm64(S1, S2, l15, q, acc);
  unsigned short* yb = d ? y1 : y0;
  #pragma unroll
  for (int mt=0;mt<4;mt++){
    #pragma unroll
    for (int r=0;r<4;r++){
      int t = mt*16 + q*4 + r; int g = ch*64 + t;
      int tph = d ? (LSEQ-1-g) : g;
      size_t rowb = ((size_t)b*LSEQ + tph)*DINNER + (size_t)h*64;
      size_t dxb_ = (tokb + t)*DINNER + (size_t)h*64;
      float et = eb2[t], di = dti[t];
      #pragma unroll
      for (int pt=0;pt<4;pt++){
        int p = pt*16 + l15;
        float v = acc[mt][pt][r]*et + b2f(yb[rowb + p]) + Dv * b2f(dtxb[dxb_ + p]) * di;
        S3[t*72 + p] = f2b(v);
      }
    }
  }
  for (int i=0;i<8;i++){
    int t = i*8 + tr; int g = ch*64 + t;
    int tph = d ? (LSEQ-1-g) : g;
    *(uint4*)(yb + ((size_t)b*LSEQ + tph)*DINNER + (size_t)h*64 + cb8) = *(uint4*)&S3[t*72 + cb8];
  }
}

// ---------------- gate: g=y*silu(z), per-dir rmsnorm, sum, ->bf16 ----------------
__global__ __launch_bounds__(256) void gate_k(const unsigned short* __restrict__ y0,
    const unsigned short* __restrict__ y1, const unsigned short* __restrict__ zcomp,
    const float* __restrict__ mnw, unsigned short* __restrict__ gsum){
  int tok = blockIdx.x; int tid = threadIdx.x;
  __shared__ float g0s[DINNER], g1s[DINNER];
  float ss0 = 0.f, ss1 = 0.f;
  for (int i=0;i<4;i++){
    int c = tid + i*256;
    float z = b2f(zcomp[(size_t)tok*DINNER + c]);
    float sz = z / (1.f + expf(-z));
    float g0 = b2f(y0[(size_t)tok*DINNER + c]) * sz;
    float g1 = b2f(y1[(size_t)tok*DINNER + c]) * sz;
    g0s[c] = g0; g1s[c] = g1;
    ss0 += g0*g0; ss1 += g1*g1;
  }
  for (int m=32;m>=1;m>>=1){ ss0 += __shfl_xor(ss0,m); ss1 += __shfl_xor(ss1,m); }
  __shared__ float w0[4], w1[4];
  int wave = tid>>6, lane = tid&63;
  if (lane==0){ w0[wave]=ss0; w1[wave]=ss1; }
  __syncthreads();
  ss0 = w0[0]+w0[1]+w0[2]+w0[3];
  ss1 = w1[0]+w1[1]+w1[2]+w1[3];
  float r0 = rsqrtf(ss0*(1.f/DINNER) + 1e-5f);
  float r1 = rsqrtf(ss1*(1.f/DINNER) + 1e-5f);
  for (int i=0;i<4;i++){
    int c = tid + i*256;
    gsum[(size_t)tok*DINNER + c] = f2b((g0s[c]*r0 + g1s[c]*r1) * mnw[c]);
  }
}

extern "C" void kernel_launch(void* const* d_in, const int* in_sizes, int n_in,
                              void* d_out, int out_size, void* d_ws, size_t ws_size,
                              hipStream_t stream){
  const float* x       = (const float*)d_in[0];
  const float* nin_w   = (const float*)d_in[1];
  const float* nin_b   = (const float*)d_in[2];
  const float* nout_w  = (const float*)d_in[3];
  const float* nout_b  = (const float*)d_in[4];
  const float* in_w    = (const float*)d_in[5];
  const float* conv_w  = (const float*)d_in[6];
  const float* conv_b  = (const float*)d_in[7];
  const float* dt_bias = (const float*)d_in[8];
  const float* A_log   = (const float*)d_in[9];
  const float* D_h     = (const float*)d_in[10];
  const float* mnorm_w = (const float*)d_in[11];
  const float* out_w   = (const float*)d_in[12];
  const float* ff_w1   = (const float*)d_in[13];
  const float* ff_b1   = (const float*)d_in[14];
  const float* ff_w2   = (const float*)d_in[15];
  const float* ff_b2   = (const float*)d_in[16];
  float* out = (float*)d_out;

  char* ws = (char*)d_ws;
  size_t off = 0;
  auto alloc = [&](size_t bytes)->char*{
    char* p = ws + off; off = (off + bytes + 255) & ~(size_t)255; return p; };
  unsigned short* xn_bf = (unsigned short*)alloc((size_t)NTOK*DMODEL*2);
  unsigned short* in_wT = (unsigned short*)alloc((size_t)NPAD*DMODEL*2);
  unsigned short* out_wT= (unsigned short*)alloc((size_t)DMODEL*DINNER*2);
  unsigned short* w1T   = (unsigned short*)alloc((size_t)2048*DMODEL*2);
  unsigned short* w2T   = (unsigned short*)alloc((size_t)DMODEL*2048*2);
  unsigned short* zx    = (unsigned short*)alloc((size_t)NTOK*NPAD*2);      // 37.7 MB
  unsigned short* zcomp = (unsigned short*)alloc((size_t)NTOK*DINNER*2);    // 16.8 MB
  float*          dAb   = (float*)alloc((size_t)2*NTOK*NHEADS*4);
  float*          dtb   = (float*)alloc((size_t)2*NTOK*NHEADS*4);
  unsigned short* Bb    = (unsigned short*)alloc((size_t)2*NTOK*DSTATE*2);
  unsigned short* Cb    = (unsigned short*)alloc((size_t)2*NTOK*DSTATE*2);
  unsigned short* dtxb  = (unsigned short*)alloc((size_t)2*NTOK*DINNER*2);  // 33.6 MB
  unsigned short* y0    = (unsigned short*)alloc((size_t)NTOK*DINNER*2);    // 16.8 MB
  unsigned short* y1    = (unsigned short*)alloc((size_t)NTOK*DINNER*2);    // 16.8 MB
  float*          Pch   = (float*)alloc((size_t)64*NCH*4);
  float*          ebuf  = (float*)alloc((size_t)64*NCH*64*4);               // 1.05 MB
  size_t need = off;
  if (need > ws_size) return;  // fail absmax cleanly instead of faulting

  // aliases into sequentially-dead regions:
  unsigned short* hbuf  = zx;                          // chunk states; zx dead after conv kernels
  unsigned short* gsum  = dtxb;                        // dtxb dead after ssd2_k
  float* mpre = (float*)(dtxb + (size_t)NTOK*DINNER);  // 2nd half of dtxb
  unsigned short* m_bf  = y0;                          // y0 dead after gate_k
  unsigned short* h1    = zx;                          // hbuf dead after ssd2_k

  // weight transposes -> bf16 [N][K]
  wconv_t<<<dim3(NPAD/32,   DMODEL/32), 256, 0, stream>>>(in_w,  in_wT,  DMODEL, DPROJ,  NPAD);
  wconv_t<<<dim3(DMODEL/32, DINNER/32), 256, 0, stream>>>(out_w, out_wT, DINNER, DMODEL, DMODEL);
  wconv_t<<<dim3(2048/32,   DMODEL/32), 256, 0, stream>>>(ff_w1, w1T,    DMODEL, 2048,   2048);
  wconv_t<<<dim3(DMODEL/32, 2048/32),   256, 0, stream>>>(ff_w2, w2T,    2048,   DMODEL, DMODEL);
  // LN in -> bf16
  layernorm_k<<<NTOK, 256, 0, stream>>>(x, nin_w, nin_b, xn_bf);
  // in_proj (shared between directions) -> bf16 zx
  gemm_k<128><<<dim3(NPAD/128, NTOK/128), 256, 0, stream>>>(xn_bf, in_wT, zx, NTOK, NPAD, DMODEL, 3, nullptr, nullptr);
  // dt/dA then conv (both directions from one pass) + z compaction
  dt_k<<<dim3(LSEQ/16, BSZ), 256, 0, stream>>>(zx, dt_bias, A_log, dAb, dtb);
  conv_x_k<<<dim3(LSEQ/32, BSZ), 256, 0, stream>>>(zx, conv_w, conv_b, dtb, dtxb, zcomp);
  conv_bc_k<<<dim3(LSEQ/64, BSZ), 256, 0, stream>>>(zx, conv_w, conv_b, Bb, Cb);
  // chunked SSD: intra-chunk (MFMA) -> combine -> inter-chunk (MFMA)
  ssd1_k<<<dim3(NCH, NHEADS, 2*BSZ), 64, 0, stream>>>(dAb, dtxb, Bb, Cb, y0, y1, hbuf, Pch, ebuf);
  comb_k<<<64, 256, 0, stream>>>(hbuf, Pch);
  ssd2_k<<<dim3(NCH, NHEADS, 2*BSZ), 64, 0, stream>>>(Cb, hbuf, dtxb, dtb, ebuf, D_h, y0, y1);
  // gate + per-dir rmsnorm + sum (linearity: single out_proj GEMM)
  gate_k<<<NTOK, 256, 0, stream>>>(y0, y1, zcomp, mnorm_w, gsum);
  // out_proj -> f32 mpre  (N=512: TN=64 tile, 512 blocks)
  gemm_k<64><<<dim3(DMODEL/64, NTOK/128), 256, 0, stream>>>(gsum, out_wT, mpre, NTOK, DMODEL, DINNER, 0, nullptr, nullptr);
  // LN out -> bf16
  layernorm_k<<<NTOK, 256, 0, stream>>>(mpre, nout_w, nout_b, m_bf);
  // ff1 + gelu -> bf16
  gemm_k<128><<<dim3(2048/128, NTOK/128), 256, 0, stream>>>(m_bf, w1T, h1, NTOK, 2048, DMODEL, 1, ff_b1, nullptr);
  // ff2 + bias + residual -> f32 out  (N=512: TN=64 tile)
  gemm_k<64><<<dim3(DMODEL/64, NTOK/128), 256, 0, stream>>>(h1, w2T, out, NTOK, DMODEL, 2048, 2, ff_b2, x);
}

// Round 10
// 472.136 us; speedup vs baseline: 1.0347x; 1.0347x over previous
//
#include <hip/hip_runtime.h>
#include <hip/hip_bf16.h>

#define LSEQ 4096
#define BSZ 2
#define DMODEL 512
#define DINNER 1024
#define DSTATE 64
#define NHEADS 16
#define CONVDIM 1152
#define DPROJ 2192
#define NPAD 2304
#define NTOK (BSZ*LSEQ)
#define NCH 64   /* 64-token chunks */

typedef __attribute__((ext_vector_type(8))) short short8;
typedef __attribute__((ext_vector_type(4))) float f32x4;

__device__ inline unsigned short f2b(float v){
  unsigned int u = __builtin_bit_cast(unsigned int, v);
  unsigned int r = (u + 0x7FFFu + ((u >> 16) & 1u)) >> 16;
  return (unsigned short)r;
}
__device__ inline float b2f(unsigned short u){
  unsigned int x = ((unsigned int)u) << 16;
  return __builtin_bit_cast(float, x);
}
__device__ inline uint4 pack8(const float* v){
  uint4 pk;
  pk.x = (unsigned)f2b(v[0]) | ((unsigned)f2b(v[1])<<16);
  pk.y = (unsigned)f2b(v[2]) | ((unsigned)f2b(v[3])<<16);
  pk.z = (unsigned)f2b(v[4]) | ((unsigned)f2b(v[5])<<16);
  pk.w = (unsigned)f2b(v[6]) | ((unsigned)f2b(v[7])<<16);
  return pk;
}

#define GLL16(gp, lp) __builtin_amdgcn_global_load_lds( \
    (const __attribute__((address_space(1))) unsigned int*)(gp), \
    (__attribute__((address_space(3))) unsigned int*)(lp), 16, 0, 0)

// ---------------- weight transpose + f32->bf16 (src [K][Nsrc] -> dst [Npad][K]) ----
__global__ __launch_bounds__(256) void wconv_t(const float* __restrict__ src,
    unsigned short* __restrict__ dst, int K, int Nsrc, int Npad){
  __shared__ float t[32][33];
  int n0 = blockIdx.x*32, k0 = blockIdx.y*32;
  int tx = threadIdx.x & 31, ty = threadIdx.x >> 5;
  for (int i=0;i<4;i++){
    int k = k0 + ty + i*8; int n = n0 + tx;
    t[ty + i*8][tx] = (n < Nsrc) ? src[(size_t)k*Nsrc + n] : 0.f;
  }
  __syncthreads();
  for (int i=0;i<4;i++){
    int n = n0 + ty + i*8; int k = k0 + tx;
    if (n < Npad) dst[(size_t)n*K + k] = f2b(t[tx][ty + i*8]);
  }
}

// ---------------- layernorm over 512 cols (f32 in) -> bf16 ----------------
__global__ __launch_bounds__(256) void layernorm_k(const float* __restrict__ in,
    const float* __restrict__ w, const float* __restrict__ bb, unsigned short* __restrict__ out){
  int row = blockIdx.x; int tid = threadIdx.x;
  const float* r = in + (size_t)row*DMODEL;
  float v0 = r[tid], v1 = r[tid+256];
  float s = v0+v1, sq = v0*v0+v1*v1;
  for (int m=32;m>=1;m>>=1){ s += __shfl_xor(s,m); sq += __shfl_xor(sq,m); }
  __shared__ float ws_[4], wq_[4];
  int wave = tid>>6, lane = tid&63;
  if (lane==0){ ws_[wave]=s; wq_[wave]=sq; }
  __syncthreads();
  s = ws_[0]+ws_[1]+ws_[2]+ws_[3]; sq = wq_[0]+wq_[1]+wq_[2]+wq_[3];
  float mu = s * (1.f/DMODEL);
  float var = sq * (1.f/DMODEL) - mu*mu;
  float rs = rsqrtf(var + 1e-5f);
  out[(size_t)row*DMODEL + tid]     = f2b((v0-mu)*rs*w[tid] + bb[tid]);
  out[(size_t)row*DMODEL + tid+256] = f2b((v1-mu)*rs*w[tid+256] + bb[tid+256]);
}

// ---------------- bf16 MFMA GEMM: C[M,N] = A[M,K] @ Bt[N,K]^T ----------------
// Staging via global_load_lds width=16 (async direct-to-LDS, unpadded [128][32]).
// epi 0: f32 plain ; 1: bf16 gelu(v+bias) ; 2: f32 v+bias+resid ; 3: bf16 plain
__global__ __launch_bounds__(256) void gemm_k(const unsigned short* __restrict__ A,
    const unsigned short* __restrict__ Bt, void* __restrict__ outp,
    int M, int N, int K, int epi, const float* __restrict__ bias, const float* __restrict__ resid){
  __shared__ __align__(16) unsigned short smem[8320];   // 16640 B: staging 16384, epilogue 16640
  unsigned short* As = smem;                // [128][32]
  unsigned short* Bs = smem + 128*32;       // [128][32]
  int tid = threadIdx.x;
  int lane = tid & 63, wave = tid >> 6;
  int wr = wave >> 1, wc = wave & 1;
  int l15 = lane & 15, q = lane >> 4;
  int bm = blockIdx.y, bn = blockIdx.x;
  f32x4 acc[4][4];
  for (int i=0;i<4;i++) for(int j=0;j<4;j++) acc[i][j] = (f32x4){0.f,0.f,0.f,0.f};
  const size_t abase = (size_t)bm*128*K;
  const size_t bbase = (size_t)bn*128*K;
  for (int k0 = 0; k0 < K; k0 += 32){
    #pragma unroll
    for (int i=0;i<2;i++){
      int idx = tid + i*256; int rr = idx>>2, cg = idx&3;
      GLL16(A  + abase + (size_t)rr*K + k0 + cg*8, As + idx*8);
      GLL16(Bt + bbase + (size_t)rr*K + k0 + cg*8, Bs + idx*8);
    }
    __syncthreads();
    short8 af[4], bfr[4];
    for (int mt=0;mt<4;mt++) af[mt]  = *(const short8*)(&As[(wr*64+mt*16+l15)*32 + q*8]);
    for (int nt=0;nt<4;nt++) bfr[nt] = *(const short8*)(&Bs[(wc*64+nt*16+l15)*32 + q*8]);
    for (int mt=0;mt<4;mt++)
      for (int nt=0;nt<4;nt++)
        acc[mt][nt] = __builtin_amdgcn_mfma_f32_16x16x32_bf16(af[mt], bfr[nt], acc[mt][nt], 0,0,0);
    __syncthreads();
  }
  // ---- coalesced epilogue (per-wave 16x65-f32 LDS slab overlaying As/Bs) ----
  float* cbuf = ((float*)smem) + wave*1040;
  int rbase = q*4;
  int gr0t = bm*128 + wr*64;
  int gc0 = bn*128 + wc*64;
  for (int mt=0; mt<4; mt++){
    for (int nt=0;nt<4;nt++)
      for (int rr=0;rr<4;rr++)
        cbuf[(rbase+rr)*65 + nt*16 + l15] = acc[mt][nt][rr];
    int gr0 = gr0t + mt*16;
    if (epi == 1 || epi == 3){
      int r8 = lane >> 3, c0 = (lane & 7)*8;
      #pragma unroll
      for (int h=0; h<2; h++){
        int row = h*8 + r8;
        float v[8];
        #pragma unroll
        for (int t=0;t<8;t++) v[t] = cbuf[row*65 + c0 + t];
        if (epi == 1){
          #pragma unroll
          for (int t=0;t<8;t++){
            float bv = v[t] + bias[gc0 + c0 + t];
            v[t] = 0.5f*bv*(1.f+erff(bv*0.70710678118654752f));
          }
        }
        *(uint4*)((unsigned short*)outp + (size_t)(gr0+row)*N + gc0 + c0) = pack8(v);
      }
    } else {
      int r4 = lane >> 4, c0 = (lane & 15)*4;
      #pragma unroll
      for (int h=0; h<4; h++){
        int row = h*4 + r4;
        float4 v;
        v.x = cbuf[row*65 + c0 + 0];
        v.y = cbuf[row*65 + c0 + 1];
        v.z = cbuf[row*65 + c0 + 2];
        v.w = cbuf[row*65 + c0 + 3];
        if (epi == 2){
          const float4 rv = *(const float4*)(resid + (size_t)(gr0+row)*N + gc0 + c0);
          v.x += bias[gc0+c0+0] + rv.x;
          v.y += bias[gc0+c0+1] + rv.y;
          v.z += bias[gc0+c0+2] + rv.z;
          v.w += bias[gc0+c0+3] + rv.w;
        }
        *(float4*)((float*)outp + (size_t)(gr0+row)*N + gc0 + c0) = v;
      }
    }
  }
}

// ---------------- dt/dA per (token, head), written for both directions ----------------
__global__ __launch_bounds__(256) void dt_k(const unsigned short* __restrict__ zx,
    const float* __restrict__ dt_bias, const float* __restrict__ A_log,
    float* __restrict__ dAb, float* __restrict__ dtb){
  int b = blockIdx.y;
  int t = blockIdx.x*16 + (threadIdx.x>>4);
  int h = threadIdx.x & 15;
  float raw = b2f(zx[((size_t)b*LSEQ + t)*NPAD + (DINNER+CONVDIM) + h]) + dt_bias[h];
  float dt = (raw > 20.f) ? raw : log1pf(expf(raw));
  float dA = expf(-expf(A_log[h]) * dt);
  size_t f = ((size_t)b*LSEQ + t)*NHEADS + h;
  size_t r = ((size_t)(BSZ+b)*LSEQ + (LSEQ-1-t))*NHEADS + h;
  dAb[f] = dA; dtb[f] = dt;
  dAb[r] = dA; dtb[r] = dt;
}

// ---------------- conv+silu for x-channels, BOTH directions, + z compaction ----------
__global__ __launch_bounds__(256) void conv_x_k(const unsigned short* __restrict__ zx,
    const float* __restrict__ conv_w, const float* __restrict__ conv_b,
    const float* __restrict__ dtb, unsigned short* __restrict__ dtxb,
    unsigned short* __restrict__ zcomp){
  int b = blockIdx.y;
  int t0blk = blockIdx.x * 32;
  int tid = threadIdx.x;
  int half = tid >> 7, cg = tid & 127;
  int c0 = cg * 8;
  int head = c0 >> 6;
  float wk[4][8], bias8[8];
  #pragma unroll
  for (int k=0;k<4;k++)
    #pragma unroll
    for (int j=0;j<8;j++) wk[k][j] = conv_w[k*CONVDIM + c0 + j];
  #pragma unroll
  for (int j=0;j<8;j++) bias8[j] = conv_b[c0 + j];
  __shared__ float sdtf[32][16], sdtb[32][16];
  for (int r = tid; r < 512; r += 256){
    int i = r >> 4, h = r & 15;
    sdtf[i][h] = dtb[((size_t)b*LSEQ + t0blk + i)*NHEADS + h];
    sdtb[i][h] = dtb[((size_t)(BSZ+b)*LSEQ + (LSEQ-1-(t0blk+i)))*NHEADS + h];
  }
  __syncthreads();
  int t0 = t0blk + half*16;
  float w0[8],w1[8],w2[8],w3[8];
  #pragma unroll
  for (int j=0;j<8;j++){ w1[j]=0.f; w2[j]=0.f; w3[j]=0.f; }
  for (int it=0; it<22; ++it){
    int t = t0 - 3 + it;
    #pragma unroll
    for (int j=0;j<8;j++){ w0[j]=w1[j]; w1[j]=w2[j]; w2[j]=w3[j]; }
    if (t >= 0 && t < LSEQ){
      uint4 xv = *(const uint4*)(zx + ((size_t)b*LSEQ + t)*NPAD + DINNER + c0);
      const unsigned short* xs = (const unsigned short*)&xv;
      #pragma unroll
      for (int j=0;j<8;j++) w3[j] = b2f(xs[j]);
      if (t >= t0 && t < t0+16){
        uint4 zv = *(const uint4*)(zx + ((size_t)b*LSEQ + t)*NPAD + c0);
        *(uint4*)(zcomp + ((size_t)b*LSEQ + t)*DINNER + c0) = zv;
      }
    } else {
      #pragma unroll
      for (int j=0;j<8;j++) w3[j] = 0.f;
    }
    if (t >= t0 && t < t0+16){
      float dtf = sdtf[t - t0blk][head];
      float v[8];
      #pragma unroll
      for (int j=0;j<8;j++){
        float a = bias8[j] + wk[0][j]*w0[j] + wk[1][j]*w1[j] + wk[2][j]*w2[j] + wk[3][j]*w3[j];
        v[j] = (a / (1.f + expf(-a))) * dtf;
      }
      *(uint4*)(dtxb + ((size_t)b*LSEQ + t)*DINNER + c0) = pack8(v);
    }
    int tau = t - 3;
    if (tau >= t0 && tau < t0+16){
      float dtv = sdtb[tau - t0blk][head];
      float v[8];
      #pragma unroll
      for (int j=0;j<8;j++){
        float a = bias8[j] + wk[0][j]*w3[j] + wk[1][j]*w2[j] + wk[2][j]*w1[j] + wk[3][j]*w0[j];
        v[j] = (a / (1.f + expf(-a))) * dtv;
      }
      *(uint4*)(dtxb + ((size_t)(BSZ+b)*LSEQ + (LSEQ-1-tau))*DINNER + c0) = pack8(v);
    }
  }
}

// ---------------- conv+silu for B/C channels, both directions ----------------
__global__ __launch_bounds__(256) void conv_bc_k(const unsigned short* __restrict__ zx,
    const float* __restrict__ conv_w, const float* __restrict__ conv_b,
    unsigned short* __restrict__ Bb, unsigned short* __restrict__ Cb){
  int b = blockIdx.y;
  int t0blk = blockIdx.x * 64;
  int tid = threadIdx.x;
  int slot = tid >> 4, cg = tid & 15;
  int c0 = cg*8;
  int ccol = DINNER + 1024 + c0;
  int cw = 1024 + c0;
  float wk[4][8], bias8[8];
  #pragma unroll
  for (int k=0;k<4;k++)
    #pragma unroll
    for (int j=0;j<8;j++) wk[k][j] = conv_w[k*CONVDIM + cw + j];
  #pragma unroll
  for (int j=0;j<8;j++) bias8[j] = conv_b[cw + j];
  int t0 = t0blk + slot*4;
  float w0[8],w1[8],w2[8],w3[8];
  #pragma unroll
  for (int j=0;j<8;j++){ w1[j]=0.f; w2[j]=0.f; w3[j]=0.f; }
  for (int it=0; it<10; ++it){
    int t = t0 - 3 + it;
    #pragma unroll
    for (int j=0;j<8;j++){ w0[j]=w1[j]; w1[j]=w2[j]; w2[j]=w3[j]; }
    if (t >= 0 && t < LSEQ){
      uint4 xv = *(const uint4*)(zx + ((size_t)b*LSEQ + t)*NPAD + ccol);
      const unsigned short* xs = (const unsigned short*)&xv;
      #pragma unroll
      for (int j=0;j<8;j++) w3[j] = b2f(xs[j]);
    } else {
      #pragma unroll
      for (int j=0;j<8;j++) w3[j] = 0.f;
    }
    if (t >= t0 && t < t0+4){
      float v[8];
      #pragma unroll
      for (int j=0;j<8;j++){
        float a = bias8[j] + wk[0][j]*w0[j] + wk[1][j]*w1[j] + wk[2][j]*w2[j] + wk[3][j]*w3[j];
        v[j] = a / (1.f + expf(-a));
      }
      size_t tok = (size_t)b*LSEQ + t;
      if (c0 < 64) *(uint4*)(Bb + tok*DSTATE + c0)      = pack8(v);
      else         *(uint4*)(Cb + tok*DSTATE + (c0-64)) = pack8(v);
    }
    int tau = t - 3;
    if (tau >= t0 && tau < t0+4){
      float v[8];
      #pragma unroll
      for (int j=0;j<8;j++){
        float a = bias8[j] + wk[0][j]*w3[j] + wk[1][j]*w2[j] + wk[2][j]*w1[j] + wk[3][j]*w0[j];
        v[j] = a / (1.f + expf(-a));
      }
      size_t tok = (size_t)(BSZ+b)*LSEQ + (LSEQ-1-tau);
      if (c0 < 64) *(uint4*)(Bb + tok*DSTATE + c0)      = pack8(v);
      else         *(uint4*)(Cb + tok*DSTATE + (c0-64)) = pack8(v);
    }
  }
}

// ---- 64x64x64 bf16 GEMM on one wave: D += A(S-rows m, k contiguous) * B(S-rows n)^T
__device__ inline void gemm64(const unsigned short* Ab, const unsigned short* Bb_,
                              int l15, int q, f32x4 acc[4][4]){
  #pragma unroll
  for (int ks=0; ks<2; ks++){
    short8 af[4], bf4[4];
    #pragma unroll
    for (int mt=0;mt<4;mt++) af[mt]  = *(const short8*)(Ab  + (mt*16+l15)*72 + ks*32 + q*8);
    #pragma unroll
    for (int nt=0;nt<4;nt++) bf4[nt] = *(const short8*)(Bb_ + (nt*16+l15)*72 + ks*32 + q*8);
    #pragma unroll
    for (int mt=0;mt<4;mt++)
      #pragma unroll
      for (int nt=0;nt<4;nt++)
        acc[mt][nt] = __builtin_amdgcn_mfma_f32_16x16x32_bf16(af[mt], bf4[nt], acc[mt][nt], 0,0,0);
  }
}

// ---------------- SSD pass 1: per chunk: Y_intra (masked attention form) + local state G ----
// Transpose scatters use per-lane rotated order (jj = (j + lane&7) & 7): with row
// stride 72 shorts, an 8-row step is bank-aligned, so un-rotated scatters hit
// 8-way conflicts (8.26M SQ_LDS_BANK_CONFLICT in r9); rotation spreads to ~2-way.
__global__ __launch_bounds__(64) void ssd1_k(const float* __restrict__ dAb,
    const unsigned short* __restrict__ dtxb, const unsigned short* __restrict__ Bb,
    const unsigned short* __restrict__ Cb,
    unsigned short* __restrict__ y0, unsigned short* __restrict__ y1,
    unsigned short* __restrict__ hbuf, float* __restrict__ Pch, float* __restrict__ ebuf){
  int ch = blockIdx.x, h = blockIdx.y, z = blockIdx.z;
  int d = z >> 1, b = z & 1;
  int lane = threadIdx.x;
  int l15 = lane & 15, q = lane >> 4;
  int tr = lane >> 3, cb8 = (lane & 7)*8;
  int c7 = lane & 7;
  size_t tokb = (size_t)z*LSEQ + (size_t)ch*64;
  size_t zhc = ((size_t)z*NHEADS + h)*NCH + ch;
  __shared__ __align__(16) unsigned short S1[64*72];
  __shared__ __align__(16) unsigned short S2[64*72];
  __shared__ __align__(16) unsigned short S3[64*72];
  __shared__ float Lb[64];
  float L = fmaxf(logf(dAb[(tokb + lane)*NHEADS + h]), -60.f);
  #pragma unroll
  for (int off=1; off<64; off<<=1){
    float v = __shfl_up(L, off);
    if (lane >= off) L += v;
  }
  Lb[lane] = L;
  float e = expf(L);
  ebuf[zhc*64 + lane] = e;
  if (lane == 63) Pch[zhc] = e;
  for (int i=0;i<8;i++){
    int t = i*8 + tr;
    *(uint4*)&S1[t*72 + cb8] = *(const uint4*)(Cb + (tokb+t)*DSTATE + cb8);
    *(uint4*)&S2[t*72 + cb8] = *(const uint4*)(Bb + (tokb+t)*DSTATE + cb8);
    uint4 xv = *(const uint4*)(dtxb + (tokb+t)*DINNER + (size_t)h*64 + cb8);
    const unsigned short* xs = (const unsigned short*)&xv;
    #pragma unroll
    for (int j=0;j<8;j++){
      int jj = (j + c7) & 7;                 // bank-spread rotation
      S3[(cb8+jj)*72 + t] = xs[jj];
    }
  }
  f32x4 sa[4][4];
  for (int i=0;i<4;i++) for (int j=0;j<4;j++) sa[i][j] = (f32x4){0.f,0.f,0.f,0.f};
  gemm64(S1, S2, l15, q, sa);
  float Lsv[4];
  #pragma unroll
  for (int nt=0;nt<4;nt++) Lsv[nt] = Lb[nt*16 + l15];
  #pragma unroll
  for (int mt=0;mt<4;mt++){
    #pragma unroll
    for (int r=0;r<4;r++){
      int t = mt*16 + q*4 + r;
      float Lt = Lb[t];
      #pragma unroll
      for (int nt=0;nt<4;nt++){
        int s = nt*16 + l15;
        float v = (t >= s) ? expf(Lt - Lsv[nt]) * sa[mt][nt][r] : 0.f;
        S1[t*72 + s] = f2b(v);
      }
    }
  }
  f32x4 ya[4][4];
  for (int i=0;i<4;i++) for (int j=0;j<4;j++) ya[i][j] = (f32x4){0.f,0.f,0.f,0.f};
  gemm64(S1, S3, l15, q, ya);
  #pragma unroll
  for (int mt=0;mt<4;mt++)
    #pragma unroll
    for (int pt=0;pt<4;pt++)
      #pragma unroll
      for (int r=0;r<4;r++)
        S2[(mt*16+q*4+r)*72 + pt*16 + l15] = f2b(ya[mt][pt][r]);
  unsigned short* yb = d ? y1 : y0;
  for (int i=0;i<8;i++){
    int t = i*8 + tr; int g = ch*64 + t;
    int tph = d ? (LSEQ-1-g) : g;
    *(uint4*)(yb + ((size_t)b*LSEQ + tph)*DINNER + (size_t)h*64 + cb8) = *(uint4*)&S2[t*72 + cb8];
  }
  float L63 = Lb[63];
  for (int i=0;i<8;i++){
    int s = i*8 + tr;
    float w = expf(L63 - Lb[s]);
    uint4 bv = *(const uint4*)(Bb + (tokb+s)*DSTATE + cb8);
    const unsigned short* bs = (const unsigned short*)&bv;
    #pragma unroll
    for (int j=0;j<8;j++){
      int jj = (j + c7) & 7;                 // bank-spread rotation
      S2[(cb8+jj)*72 + s] = f2b(w * b2f(bs[jj]));
    }
  }
  f32x4 ga[4][4];
  for (int i=0;i<4;i++) for (int j=0;j<4;j++) ga[i][j] = (f32x4){0.f,0.f,0.f,0.f};
  gemm64(S3, S2, l15, q, ga);
  #pragma unroll
  for (int pt=0;pt<4;pt++)
    #pragma unroll
    for (int nt=0;nt<4;nt++)
      #pragma unroll
      for (int r=0;r<4;r++)
        S1[(pt*16+q*4+r)*72 + nt*16 + l15] = f2b(ga[pt][nt][r]);
  for (int i=0;i<8;i++){
    int p = i*8 + tr;
    *(uint4*)(hbuf + zhc*4096 + (size_t)p*64 + cb8) = *(uint4*)&S1[p*72 + cb8];
  }
}

// ---------------- combine chunk states, IN PLACE ----------------
__global__ __launch_bounds__(256) void comb_k(unsigned short* __restrict__ hbuf,
    const float* __restrict__ Pch){
  int u = blockIdx.x; int tid = threadIdx.x;
  float hreg[16];
  #pragma unroll
  for (int k=0;k<16;k++) hreg[k]=0.f;
  for (int ch=0; ch<NCH; ch++){
    size_t base = ((size_t)u*NCH + ch)*4096;
    float P = Pch[(size_t)u*NCH + ch];
    #pragma unroll
    for (int k=0;k<16;k++){
      float t = b2f(hbuf[base + tid + k*256]);
      hbuf[base + tid + k*256] = f2b(hreg[k]);
      hreg[k] = hreg[k]*P + t;
    }
  }
}

// ---------------- SSD pass 2: Y += diag(e) C h_in^T + D*xh ----------------
__global__ __launch_bounds__(64) void ssd2_k(const unsigned short* __restrict__ Cb,
    const unsigned short* __restrict__ hbuf, const unsigned short* __restrict__ dtxb,
    const float* __restrict__ dtb, const float* __restrict__ ebuf, const float* __restrict__ Dh,
    unsigned short* __restrict__ y0, unsigned short* __restrict__ y1){
  int ch = blockIdx.x, h = blockIdx.y, z = blockIdx.z;
  int d = z >> 1, b = z & 1;
  int lane = threadIdx.x;
  int l15 = lane & 15, q = lane >> 4;
  int tr = lane >> 3, cb8 = (lane & 7)*8;
  size_t tokb = (size_t)z*LSEQ + (size_t)ch*64;
  size_t zhc = ((size_t)z*NHEADS + h)*NCH + ch;
  __shared__ __align__(16) unsigned short S1[64*72];
  __shared__ __align__(16) unsigned short S2[64*72];
  __shared__ __align__(16) unsigned short S3[64*72];
  __shared__ float eb2[64], dti[64];
  eb2[lane] = ebuf[zhc*64 + lane];
  dti[lane] = 1.f / dtb[(tokb + lane)*NHEADS + h];
  float Dv = Dh[h];
  for (int i=0;i<8;i++){
    int t = i*8 + tr;
    *(uint4*)&S1[t*72 + cb8] = *(const uint4*)(Cb + (tokb+t)*DSTATE + cb8);
    *(uint4*)&S2[t*72 + cb8] = *(const uint4*)(hbuf + zhc*4096 + (size_t)t*64 + cb8);
  }
  f32x4 acc[4][4];
  for (int i=0;i<4;i++) for (int j=0;j<4;j++) acc[i][j] = (f32x4){0.f,0.f,0.f,0.f};
  gemm64(S1, S2, l15, q, acc);
  unsigned short* yb = d ? y1 : y0;
  #pragma unroll
  for (int mt=0;mt<4;mt++){
    #pragma unroll
    for (int r=0;r<4;r++){
      int t = mt*16 + q*4 + r; int g = ch*64 + t;
      int tph = d ? (LSEQ-1-g) : g;
      size_t rowb = ((size_t)b*LSEQ + tph)*DINNER + (size_t)h*64;
      size_t dxb_ = (tokb + t)*DINNER + (size_t)h*64;
      float et = eb2[t], di = dti[t];
      #pragma unroll
      for (int pt=0;pt<4;pt++){
        int p = pt*16 + l15;
        float v = acc[mt][pt][r]*et + b2f(yb[rowb + p]) + Dv * b2f(dtxb[dxb_ + p]) * di;
        S3[t*72 + p] = f2b(v);
      }
    }
  }
  for (int i=0;i<8;i++){
    int t = i*8 + tr; int g = ch*64 + t;
    int tph = d ? (LSEQ-1-g) : g;
    *(uint4*)(yb + ((size_t)b*LSEQ + tph)*DINNER + (size_t)h*64 + cb8) = *(uint4*)&S3[t*72 + cb8];
  }
}

// ---------------- gate: g=y*silu(z), per-dir rmsnorm, sum, ->bf16 ----------------
__global__ __launch_bounds__(256) void gate_k(const unsigned short* __restrict__ y0,
    const unsigned short* __restrict__ y1, const unsigned short* __restrict__ zcomp,
    const float* __restrict__ mnw, unsigned short* __restrict__ gsum){
  int tok = blockIdx.x; int tid = threadIdx.x;
  __shared__ float g0s[DINNER], g1s[DINNER];
  float ss0 = 0.f, ss1 = 0.f;
  for (int i=0;i<4;i++){
    int c = tid + i*256;
    float z = b2f(zcomp[(size_t)tok*DINNER + c]);
    float sz = z / (1.f + expf(-z));
    float g0 = b2f(y0[(size_t)tok*DINNER + c]) * sz;
    float g1 = b2f(y1[(size_t)tok*DINNER + c]) * sz;
    g0s[c] = g0; g1s[c] = g1;
    ss0 += g0*g0; ss1 += g1*g1;
  }
  for (int m=32;m>=1;m>>=1){ ss0 += __shfl_xor(ss0,m); ss1 += __shfl_xor(ss1,m); }
  __shared__ float w0[4], w1[4];
  int wave = tid>>6, lane = tid&63;
  if (lane==0){ w0[wave]=ss0; w1[wave]=ss1; }
  __syncthreads();
  ss0 = w0[0]+w0[1]+w0[2]+w0[3];
  ss1 = w1[0]+w1[1]+w1[2]+w1[3];
  float r0 = rsqrtf(ss0*(1.f/DINNER) + 1e-5f);
  float r1 = rsqrtf(ss1*(1.f/DINNER) + 1e-5f);
  for (int i=0;i<4;i++){
    int c = tid + i*256;
    gsum[(size_t)tok*DINNER + c] = f2b((g0s[c]*r0 + g1s[c]*r1) * mnw[c]);
  }
}

extern "C" void kernel_launch(void* const* d_in, const int* in_sizes, int n_in,
                              void* d_out, int out_size, void* d_ws, size_t ws_size,
                              hipStream_t stream){
  const float* x       = (const float*)d_in[0];
  const float* nin_w   = (const float*)d_in[1];
  const float* nin_b   = (const float*)d_in[2];
  const float* nout_w  = (const float*)d_in[3];
  const float* nout_b  = (const float*)d_in[4];
  const float* in_w    = (const float*)d_in[5];
  const float* conv_w  = (const float*)d_in[6];
  const float* conv_b  = (const float*)d_in[7];
  const float* dt_bias = (const float*)d_in[8];
  const float* A_log   = (const float*)d_in[9];
  const float* D_h     = (const float*)d_in[10];
  const float* mnorm_w = (const float*)d_in[11];
  const float* out_w   = (const float*)d_in[12];
  const float* ff_w1   = (const float*)d_in[13];
  const float* ff_b1   = (const float*)d_in[14];
  const float* ff_w2   = (const float*)d_in[15];
  const float* ff_b2   = (const float*)d_in[16];
  float* out = (float*)d_out;

  char* ws = (char*)d_ws;
  size_t off = 0;
  auto alloc = [&](size_t bytes)->char*{
    char* p = ws + off; off = (off + bytes + 255) & ~(size_t)255; return p; };
  unsigned short* xn_bf = (unsigned short*)alloc((size_t)NTOK*DMODEL*2);
  unsigned short* in_wT = (unsigned short*)alloc((size_t)NPAD*DMODEL*2);
  unsigned short* out_wT= (unsigned short*)alloc((size_t)DMODEL*DINNER*2);
  unsigned short* w1T   = (unsigned short*)alloc((size_t)2048*DMODEL*2);
  unsigned short* w2T   = (unsigned short*)alloc((size_t)DMODEL*2048*2);
  unsigned short* zx    = (unsigned short*)alloc((size_t)NTOK*NPAD*2);      // 37.7 MB
  unsigned short* zcomp = (unsigned short*)alloc((size_t)NTOK*DINNER*2);    // 16.8 MB
  float*          dAb   = (float*)alloc((size_t)2*NTOK*NHEADS*4);
  float*          dtb   = (float*)alloc((size_t)2*NTOK*NHEADS*4);
  unsigned short* Bb    = (unsigned short*)alloc((size_t)2*NTOK*DSTATE*2);
  unsigned short* Cb    = (unsigned short*)alloc((size_t)2*NTOK*DSTATE*2);
  unsigned short* dtxb  = (unsigned short*)alloc((size_t)2*NTOK*DINNER*2);  // 33.6 MB
  unsigned short* y0    = (unsigned short*)alloc((size_t)NTOK*DINNER*2);    // 16.8 MB
  unsigned short* y1    = (unsigned short*)alloc((size_t)NTOK*DINNER*2);    // 16.8 MB
  float*          Pch   = (float*)alloc((size_t)64*NCH*4);
  float*          ebuf  = (float*)alloc((size_t)64*NCH*64*4);               // 1.05 MB
  size_t need = off;
  if (need > ws_size) return;  // fail absmax cleanly instead of faulting

  // aliases into sequentially-dead regions:
  unsigned short* hbuf  = zx;                          // chunk states; zx dead after conv kernels
  unsigned short* gsum  = dtxb;                        // dtxb dead after ssd2_k
  float* mpre = (float*)(dtxb + (size_t)NTOK*DINNER);  // 2nd half of dtxb
  unsigned short* m_bf  = y0;                          // y0 dead after gate_k
  unsigned short* h1    = zx;                          // hbuf dead after ssd2_k

  // weight transposes -> bf16 [N][K]
  wconv_t<<<dim3(NPAD/32,   DMODEL/32), 256, 0, stream>>>(in_w,  in_wT,  DMODEL, DPROJ,  NPAD);
  wconv_t<<<dim3(DMODEL/32, DINNER/32), 256, 0, stream>>>(out_w, out_wT, DINNER, DMODEL, DMODEL);
  wconv_t<<<dim3(2048/32,   DMODEL/32), 256, 0, stream>>>(ff_w1, w1T,    DMODEL, 2048,   2048);
  wconv_t<<<dim3(DMODEL/32, 2048/32),   256, 0, stream>>>(ff_w2, w2T,    2048,   DMODEL, DMODEL);
  // LN in -> bf16
  layernorm_k<<<NTOK, 256, 0, stream>>>(x, nin_w, nin_b, xn_bf);
  // in_proj (shared between directions) -> bf16 zx
  gemm_k<<<dim3(NPAD/128, NTOK/128), 256, 0, stream>>>(xn_bf, in_wT, zx, NTOK, NPAD, DMODEL, 3, nullptr, nullptr);
  // dt/dA then conv (both directions from one pass) + z compaction
  dt_k<<<dim3(LSEQ/16, BSZ), 256, 0, stream>>>(zx, dt_bias, A_log, dAb, dtb);
  conv_x_k<<<dim3(LSEQ/32, BSZ), 256, 0, stream>>>(zx, conv_w, conv_b, dtb, dtxb, zcomp);
  conv_bc_k<<<dim3(LSEQ/64, BSZ), 256, 0, stream>>>(zx, conv_w, conv_b, Bb, Cb);
  // chunked SSD: intra-chunk (MFMA) -> combine -> inter-chunk (MFMA)
  ssd1_k<<<dim3(NCH, NHEADS, 2*BSZ), 64, 0, stream>>>(dAb, dtxb, Bb, Cb, y0, y1, hbuf, Pch, ebuf);
  comb_k<<<64, 256, 0, stream>>>(hbuf, Pch);
  ssd2_k<<<dim3(NCH, NHEADS, 2*BSZ), 64, 0, stream>>>(Cb, hbuf, dtxb, dtb, ebuf, D_h, y0, y1);
  // gate + per-dir rmsnorm + sum (linearity: single out_proj GEMM)
  gate_k<<<NTOK, 256, 0, stream>>>(y0, y1, zcomp, mnorm_w, gsum);
  // out_proj -> f32 mpre
  gemm_k<<<dim3(DMODEL/128, NTOK/128), 256, 0, stream>>>(gsum, out_wT, mpre, NTOK, DMODEL, DINNER, 0, nullptr, nullptr);
  // LN out -> bf16
  layernorm_k<<<NTOK, 256, 0, stream>>>(mpre, nout_w, nout_b, m_bf);
  // ff1 + gelu -> bf16
  gemm_k<<<dim3(2048/128, NTOK/128), 256, 0, stream>>>(m_bf, w1T, h1, NTOK, 2048, DMODEL, 1, ff_b1, nullptr);
  // ff2 + bias + residual -> f32 out
  gemm_k<<<dim3(DMODEL/128, NTOK/128), 256, 0, stream>>>(h1, w2T, out, NTOK, DMODEL, 2048, 2, ff_b2, x);
}

// Round 11
// 465.854 us; speedup vs baseline: 1.0487x; 1.0135x over previous
//
#include <hip/hip_runtime.h>
#include <hip/hip_bf16.h>

#define LSEQ 4096
#define BSZ 2
#define DMODEL 512
#define DINNER 1024
#define DSTATE 64
#define NHEADS 16
#define CONVDIM 1152
#define DPROJ 2192
#define NPAD 2304
#define NTOK (BSZ*LSEQ)
#define NCH 64   /* 64-token chunks */

typedef __attribute__((ext_vector_type(8))) short short8;
typedef __attribute__((ext_vector_type(4))) float f32x4;

__device__ inline unsigned short f2b(float v){
  unsigned int u = __builtin_bit_cast(unsigned int, v);
  unsigned int r = (u + 0x7FFFu + ((u >> 16) & 1u)) >> 16;
  return (unsigned short)r;
}
__device__ inline float b2f(unsigned short u){
  unsigned int x = ((unsigned int)u) << 16;
  return __builtin_bit_cast(float, x);
}
__device__ inline uint4 pack8(const float* v){
  uint4 pk;
  pk.x = (unsigned)f2b(v[0]) | ((unsigned)f2b(v[1])<<16);
  pk.y = (unsigned)f2b(v[2]) | ((unsigned)f2b(v[3])<<16);
  pk.z = (unsigned)f2b(v[4]) | ((unsigned)f2b(v[5])<<16);
  pk.w = (unsigned)f2b(v[6]) | ((unsigned)f2b(v[7])<<16);
  return pk;
}

#define GLL16(gp, lp) __builtin_amdgcn_global_load_lds( \
    (const __attribute__((address_space(1))) unsigned int*)(gp), \
    (__attribute__((address_space(3))) unsigned int*)(lp), 16, 0, 0)

// ---------------- weight transpose + f32->bf16 (src [K][Nsrc] -> dst [Npad][K]) ----
__global__ __launch_bounds__(256) void wconv_t(const float* __restrict__ src,
    unsigned short* __restrict__ dst, int K, int Nsrc, int Npad){
  __shared__ float t[32][33];
  int n0 = blockIdx.x*32, k0 = blockIdx.y*32;
  int tx = threadIdx.x & 31, ty = threadIdx.x >> 5;
  for (int i=0;i<4;i++){
    int k = k0 + ty + i*8; int n = n0 + tx;
    t[ty + i*8][tx] = (n < Nsrc) ? src[(size_t)k*Nsrc + n] : 0.f;
  }
  __syncthreads();
  for (int i=0;i<4;i++){
    int n = n0 + ty + i*8; int k = k0 + tx;
    if (n < Npad) dst[(size_t)n*K + k] = f2b(t[tx][ty + i*8]);
  }
}

// ---------------- layernorm over 512 cols (f32 in) -> bf16 ----------------
__global__ __launch_bounds__(256) void layernorm_k(const float* __restrict__ in,
    const float* __restrict__ w, const float* __restrict__ bb, unsigned short* __restrict__ out){
  int row = blockIdx.x; int tid = threadIdx.x;
  const float* r = in + (size_t)row*DMODEL;
  float v0 = r[tid], v1 = r[tid+256];
  float s = v0+v1, sq = v0*v0+v1*v1;
  for (int m=32;m>=1;m>>=1){ s += __shfl_xor(s,m); sq += __shfl_xor(sq,m); }
  __shared__ float ws_[4], wq_[4];
  int wave = tid>>6, lane = tid&63;
  if (lane==0){ ws_[wave]=s; wq_[wave]=sq; }
  __syncthreads();
  s = ws_[0]+ws_[1]+ws_[2]+ws_[3]; sq = wq_[0]+wq_[1]+wq_[2]+wq_[3];
  float mu = s * (1.f/DMODEL);
  float var = sq * (1.f/DMODEL) - mu*mu;
  float rs = rsqrtf(var + 1e-5f);
  out[(size_t)row*DMODEL + tid]     = f2b((v0-mu)*rs*w[tid] + bb[tid]);
  out[(size_t)row*DMODEL + tid+256] = f2b((v1-mu)*rs*w[tid+256] + bb[tid+256]);
}

// ---------------- bf16 MFMA GEMM: C[M,N] = A[M,K] @ Bt[N,K]^T ----------------
// Staging via global_load_lds width=16 (async direct-to-LDS, unpadded [128][32]).
// epi 0: f32 plain ; 1: bf16 gelu(v+bias) ; 2: f32 v+bias+resid ; 3: bf16 plain
__global__ __launch_bounds__(256) void gemm_k(const unsigned short* __restrict__ A,
    const unsigned short* __restrict__ Bt, void* __restrict__ outp,
    int M, int N, int K, int epi, const float* __restrict__ bias, const float* __restrict__ resid){
  __shared__ __align__(16) unsigned short smem[8320];   // 16640 B: staging 16384, epilogue 16640
  unsigned short* As = smem;                // [128][32]
  unsigned short* Bs = smem + 128*32;       // [128][32]
  int tid = threadIdx.x;
  int lane = tid & 63, wave = tid >> 6;
  int wr = wave >> 1, wc = wave & 1;
  int l15 = lane & 15, q = lane >> 4;
  int bm = blockIdx.y, bn = blockIdx.x;
  f32x4 acc[4][4];
  for (int i=0;i<4;i++) for(int j=0;j<4;j++) acc[i][j] = (f32x4){0.f,0.f,0.f,0.f};
  const size_t abase = (size_t)bm*128*K;
  const size_t bbase = (size_t)bn*128*K;
  for (int k0 = 0; k0 < K; k0 += 32){
    #pragma unroll
    for (int i=0;i<2;i++){
      int idx = tid + i*256; int rr = idx>>2, cg = idx&3;
      GLL16(A  + abase + (size_t)rr*K + k0 + cg*8, As + idx*8);
      GLL16(Bt + bbase + (size_t)rr*K + k0 + cg*8, Bs + idx*8);
    }
    __syncthreads();
    short8 af[4], bfr[4];
    for (int mt=0;mt<4;mt++) af[mt]  = *(const short8*)(&As[(wr*64+mt*16+l15)*32 + q*8]);
    for (int nt=0;nt<4;nt++) bfr[nt] = *(const short8*)(&Bs[(wc*64+nt*16+l15)*32 + q*8]);
    for (int mt=0;mt<4;mt++)
      for (int nt=0;nt<4;nt++)
        acc[mt][nt] = __builtin_amdgcn_mfma_f32_16x16x32_bf16(af[mt], bfr[nt], acc[mt][nt], 0,0,0);
    __syncthreads();
  }
  // ---- coalesced epilogue (per-wave 16x65-f32 LDS slab overlaying As/Bs) ----
  float* cbuf = ((float*)smem) + wave*1040;
  int rbase = q*4;
  int gr0t = bm*128 + wr*64;
  int gc0 = bn*128 + wc*64;
  for (int mt=0; mt<4; mt++){
    for (int nt=0;nt<4;nt++)
      for (int rr=0;rr<4;rr++)
        cbuf[(rbase+rr)*65 + nt*16 + l15] = acc[mt][nt][rr];
    int gr0 = gr0t + mt*16;
    if (epi == 1 || epi == 3){
      int r8 = lane >> 3, c0 = (lane & 7)*8;
      #pragma unroll
      for (int h=0; h<2; h++){
        int row = h*8 + r8;
        float v[8];
        #pragma unroll
        for (int t=0;t<8;t++) v[t] = cbuf[row*65 + c0 + t];
        if (epi == 1){
          #pragma unroll
          for (int t=0;t<8;t++){
            float bv = v[t] + bias[gc0 + c0 + t];
            v[t] = 0.5f*bv*(1.f+erff(bv*0.70710678118654752f));
          }
        }
        *(uint4*)((unsigned short*)outp + (size_t)(gr0+row)*N + gc0 + c0) = pack8(v);
      }
    } else {
      int r4 = lane >> 4, c0 = (lane & 15)*4;
      #pragma unroll
      for (int h=0; h<4; h++){
        int row = h*4 + r4;
        float4 v;
        v.x = cbuf[row*65 + c0 + 0];
        v.y = cbuf[row*65 + c0 + 1];
        v.z = cbuf[row*65 + c0 + 2];
        v.w = cbuf[row*65 + c0 + 3];
        if (epi == 2){
          const float4 rv = *(const float4*)(resid + (size_t)(gr0+row)*N + gc0 + c0);
          v.x += bias[gc0+c0+0] + rv.x;
          v.y += bias[gc0+c0+1] + rv.y;
          v.z += bias[gc0+c0+2] + rv.z;
          v.w += bias[gc0+c0+3] + rv.w;
        }
        *(float4*)((float*)outp + (size_t)(gr0+row)*N + gc0 + c0) = v;
      }
    }
  }
}

// ---------------- dt/dA per (token, head), written for both directions ----------------
__global__ __launch_bounds__(256) void dt_k(const unsigned short* __restrict__ zx,
    const float* __restrict__ dt_bias, const float* __restrict__ A_log,
    float* __restrict__ dAb, float* __restrict__ dtb){
  int b = blockIdx.y;
  int t = blockIdx.x*16 + (threadIdx.x>>4);
  int h = threadIdx.x & 15;
  float raw = b2f(zx[((size_t)b*LSEQ + t)*NPAD + (DINNER+CONVDIM) + h]) + dt_bias[h];
  float dt = (raw > 20.f) ? raw : log1pf(expf(raw));
  float dA = expf(-expf(A_log[h]) * dt);
  size_t f = ((size_t)b*LSEQ + t)*NHEADS + h;
  size_t r = ((size_t)(BSZ+b)*LSEQ + (LSEQ-1-t))*NHEADS + h;
  dAb[f] = dA; dtb[f] = dt;
  dAb[r] = dA; dtb[r] = dt;
}

// ---------------- conv+silu for x-channels, BOTH directions, + z compaction ----------
__global__ __launch_bounds__(256) void conv_x_k(const unsigned short* __restrict__ zx,
    const float* __restrict__ conv_w, const float* __restrict__ conv_b,
    const float* __restrict__ dtb, unsigned short* __restrict__ dtxb,
    unsigned short* __restrict__ zcomp){
  int b = blockIdx.y;
  int t0blk = blockIdx.x * 32;
  int tid = threadIdx.x;
  int half = tid >> 7, cg = tid & 127;
  int c0 = cg * 8;
  int head = c0 >> 6;
  float wk[4][8], bias8[8];
  #pragma unroll
  for (int k=0;k<4;k++)
    #pragma unroll
    for (int j=0;j<8;j++) wk[k][j] = conv_w[k*CONVDIM + c0 + j];
  #pragma unroll
  for (int j=0;j<8;j++) bias8[j] = conv_b[c0 + j];
  __shared__ float sdtf[32][16], sdtb[32][16];
  for (int r = tid; r < 512; r += 256){
    int i = r >> 4, h = r & 15;
    sdtf[i][h] = dtb[((size_t)b*LSEQ + t0blk + i)*NHEADS + h];
    sdtb[i][h] = dtb[((size_t)(BSZ+b)*LSEQ + (LSEQ-1-(t0blk+i)))*NHEADS + h];
  }
  __syncthreads();
  int t0 = t0blk + half*16;
  float w0[8],w1[8],w2[8],w3[8];
  #pragma unroll
  for (int j=0;j<8;j++){ w1[j]=0.f; w2[j]=0.f; w3[j]=0.f; }
  for (int it=0; it<22; ++it){
    int t = t0 - 3 + it;
    #pragma unroll
    for (int j=0;j<8;j++){ w0[j]=w1[j]; w1[j]=w2[j]; w2[j]=w3[j]; }
    if (t >= 0 && t < LSEQ){
      uint4 xv = *(const uint4*)(zx + ((size_t)b*LSEQ + t)*NPAD + DINNER + c0);
      const unsigned short* xs = (const unsigned short*)&xv;
      #pragma unroll
      for (int j=0;j<8;j++) w3[j] = b2f(xs[j]);
      if (t >= t0 && t < t0+16){
        uint4 zv = *(const uint4*)(zx + ((size_t)b*LSEQ + t)*NPAD + c0);
        *(uint4*)(zcomp + ((size_t)b*LSEQ + t)*DINNER + c0) = zv;
      }
    } else {
      #pragma unroll
      for (int j=0;j<8;j++) w3[j] = 0.f;
    }
    if (t >= t0 && t < t0+16){
      float dtf = sdtf[t - t0blk][head];
      float v[8];
      #pragma unroll
      for (int j=0;j<8;j++){
        float a = bias8[j] + wk[0][j]*w0[j] + wk[1][j]*w1[j] + wk[2][j]*w2[j] + wk[3][j]*w3[j];
        v[j] = (a / (1.f + expf(-a))) * dtf;
      }
      *(uint4*)(dtxb + ((size_t)b*LSEQ + t)*DINNER + c0) = pack8(v);
    }
    int tau = t - 3;
    if (tau >= t0 && tau < t0+16){
      float dtv = sdtb[tau - t0blk][head];
      float v[8];
      #pragma unroll
      for (int j=0;j<8;j++){
        float a = bias8[j] + wk[0][j]*w3[j] + wk[1][j]*w2[j] + wk[2][j]*w1[j] + wk[3][j]*w0[j];
        v[j] = (a / (1.f + expf(-a))) * dtv;
      }
      *(uint4*)(dtxb + ((size_t)(BSZ+b)*LSEQ + (LSEQ-1-tau))*DINNER + c0) = pack8(v);
    }
  }
}

// ---------------- conv+silu for B/C channels, both directions ----------------
__global__ __launch_bounds__(256) void conv_bc_k(const unsigned short* __restrict__ zx,
    const float* __restrict__ conv_w, const float* __restrict__ conv_b,
    unsigned short* __restrict__ Bb, unsigned short* __restrict__ Cb){
  int b = blockIdx.y;
  int t0blk = blockIdx.x * 64;
  int tid = threadIdx.x;
  int slot = tid >> 4, cg = tid & 15;
  int c0 = cg*8;
  int ccol = DINNER + 1024 + c0;
  int cw = 1024 + c0;
  float wk[4][8], bias8[8];
  #pragma unroll
  for (int k=0;k<4;k++)
    #pragma unroll
    for (int j=0;j<8;j++) wk[k][j] = conv_w[k*CONVDIM + cw + j];
  #pragma unroll
  for (int j=0;j<8;j++) bias8[j] = conv_b[cw + j];
  int t0 = t0blk + slot*4;
  float w0[8],w1[8],w2[8],w3[8];
  #pragma unroll
  for (int j=0;j<8;j++){ w1[j]=0.f; w2[j]=0.f; w3[j]=0.f; }
  for (int it=0; it<10; ++it){
    int t = t0 - 3 + it;
    #pragma unroll
    for (int j=0;j<8;j++){ w0[j]=w1[j]; w1[j]=w2[j]; w2[j]=w3[j]; }
    if (t >= 0 && t < LSEQ){
      uint4 xv = *(const uint4*)(zx + ((size_t)b*LSEQ + t)*NPAD + ccol);
      const unsigned short* xs = (const unsigned short*)&xv;
      #pragma unroll
      for (int j=0;j<8;j++) w3[j] = b2f(xs[j]);
    } else {
      #pragma unroll
      for (int j=0;j<8;j++) w3[j] = 0.f;
    }
    if (t >= t0 && t < t0+4){
      float v[8];
      #pragma unroll
      for (int j=0;j<8;j++){
        float a = bias8[j] + wk[0][j]*w0[j] + wk[1][j]*w1[j] + wk[2][j]*w2[j] + wk[3][j]*w3[j];
        v[j] = a / (1.f + expf(-a));
      }
      size_t tok = (size_t)b*LSEQ + t;
      if (c0 < 64) *(uint4*)(Bb + tok*DSTATE + c0)      = pack8(v);
      else         *(uint4*)(Cb + tok*DSTATE + (c0-64)) = pack8(v);
    }
    int tau = t - 3;
    if (tau >= t0 && tau < t0+4){
      float v[8];
      #pragma unroll
      for (int j=0;j<8;j++){
        float a = bias8[j] + wk[0][j]*w3[j] + wk[1][j]*w2[j] + wk[2][j]*w1[j] + wk[3][j]*w0[j];
        v[j] = a / (1.f + expf(-a));
      }
      size_t tok = (size_t)(BSZ+b)*LSEQ + (LSEQ-1-tau);
      if (c0 < 64) *(uint4*)(Bb + tok*DSTATE + c0)      = pack8(v);
      else         *(uint4*)(Cb + tok*DSTATE + (c0-64)) = pack8(v);
    }
  }
}

// ---- 64x64x64 bf16 GEMM on one wave: D += A(S-rows m, k contiguous) * B(S-rows n)^T
__device__ inline void gemm64(const unsigned short* Ab, const unsigned short* Bb_,
                              int l15, int q, f32x4 acc[4][4]){
  #pragma unroll
  for (int ks=0; ks<2; ks++){
    short8 af[4], bf4[4];
    #pragma unroll
    for (int mt=0;mt<4;mt++) af[mt]  = *(const short8*)(Ab  + (mt*16+l15)*72 + ks*32 + q*8);
    #pragma unroll
    for (int nt=0;nt<4;nt++) bf4[nt] = *(const short8*)(Bb_ + (nt*16+l15)*72 + ks*32 + q*8);
    #pragma unroll
    for (int mt=0;mt<4;mt++)
      #pragma unroll
      for (int nt=0;nt<4;nt++)
        acc[mt][nt] = __builtin_amdgcn_mfma_f32_16x16x32_bf16(af[mt], bf4[nt], acc[mt][nt], 0,0,0);
  }
}

// ---------------- SSD pass 1: per chunk: Y_intra (masked attention form) + local state G ----
// 2-LDS-slab version (18.7KB/block, was 28KB): S1: C->P->Y->G ; S2: B->XdtT->BwT.
// XdtT fragments captured in regs during GEMM2 (B-operand) and reused as GEMM3's
// A-operand (identical lane mapping) — eliminates the third slab.
// Transpose scatters keep the per-lane rotation (r10: conflicts 8.26M -> 0.92M).
__global__ __launch_bounds__(64) void ssd1_k(const float* __restrict__ dAb,
    const unsigned short* __restrict__ dtxb, const unsigned short* __restrict__ Bb,
    const unsigned short* __restrict__ Cb,
    unsigned short* __restrict__ y0, unsigned short* __restrict__ y1,
    unsigned short* __restrict__ hbuf, float* __restrict__ Pch, float* __restrict__ ebuf){
  int ch = blockIdx.x, h = blockIdx.y, z = blockIdx.z;
  int d = z >> 1, b = z & 1;
  int lane = threadIdx.x;
  int l15 = lane & 15, q = lane >> 4;
  int tr = lane >> 3, cb8 = (lane & 7)*8;
  int c7 = lane & 7;
  size_t tokb = (size_t)z*LSEQ + (size_t)ch*64;
  size_t zhc = ((size_t)z*NHEADS + h)*NCH + ch;
  __shared__ __align__(16) unsigned short S1[64*72];
  __shared__ __align__(16) unsigned short S2[64*72];
  __shared__ float Lb[64];
  float L = fmaxf(logf(dAb[(tokb + lane)*NHEADS + h]), -60.f);
  #pragma unroll
  for (int off=1; off<64; off<<=1){
    float v = __shfl_up(L, off);
    if (lane >= off) L += v;
  }
  Lb[lane] = L;
  float e = expf(L);
  ebuf[zhc*64 + lane] = e;
  if (lane == 63) Pch[zhc] = e;
  // stage: S1 = C rows, S2 = B rows
  for (int i=0;i<8;i++){
    int t = i*8 + tr;
    *(uint4*)&S1[t*72 + cb8] = *(const uint4*)(Cb + (tokb+t)*DSTATE + cb8);
    *(uint4*)&S2[t*72 + cb8] = *(const uint4*)(Bb + (tokb+t)*DSTATE + cb8);
  }
  // GEMM1: S = C . B^T
  f32x4 sa[4][4];
  for (int i=0;i<4;i++) for (int j=0;j<4;j++) sa[i][j] = (f32x4){0.f,0.f,0.f,0.f};
  gemm64(S1, S2, l15, q, sa);
  // mask -> P into S1 (C dead; reads precede writes in-order per wave)
  float Lsv[4];
  #pragma unroll
  for (int nt=0;nt<4;nt++) Lsv[nt] = Lb[nt*16 + l15];
  #pragma unroll
  for (int mt=0;mt<4;mt++){
    #pragma unroll
    for (int r=0;r<4;r++){
      int t = mt*16 + q*4 + r;
      float Lt = Lb[t];
      #pragma unroll
      for (int nt=0;nt<4;nt++){
        int s = nt*16 + l15;
        float v = (t >= s) ? expf(Lt - Lsv[nt]) * sa[mt][nt][r] : 0.f;
        S1[t*72 + s] = f2b(v);
      }
    }
  }
  // scatter XdtT into S2 (B dead; reloaded from global for Bw later)
  for (int i=0;i<8;i++){
    int t = i*8 + tr;
    uint4 xv = *(const uint4*)(dtxb + (tokb+t)*DINNER + (size_t)h*64 + cb8);
    const unsigned short* xs = (const unsigned short*)&xv;
    #pragma unroll
    for (int j=0;j<8;j++){
      int jj = (j + c7) & 7;                 // bank-spread rotation
      S2[(cb8+jj)*72 + t] = xs[jj];
    }
  }
  // GEMM2: Y_intra = P . Xdt ; capture XdtT fragments for GEMM3
  f32x4 ya[4][4];
  for (int i=0;i<4;i++) for (int j=0;j<4;j++) ya[i][j] = (f32x4){0.f,0.f,0.f,0.f};
  short8 xf[2][4];
  #pragma unroll
  for (int ks=0; ks<2; ks++){
    short8 afP[4];
    #pragma unroll
    for (int mt=0;mt<4;mt++) afP[mt] = *(const short8*)(S1 + (mt*16+l15)*72 + ks*32 + q*8);
    #pragma unroll
    for (int nt=0;nt<4;nt++) xf[ks][nt] = *(const short8*)(S2 + (nt*16+l15)*72 + ks*32 + q*8);
    #pragma unroll
    for (int mt=0;mt<4;mt++)
      #pragma unroll
      for (int nt=0;nt<4;nt++)
        ya[mt][nt] = __builtin_amdgcn_mfma_f32_16x16x32_bf16(afP[mt], xf[ks][nt], ya[mt][nt], 0,0,0);
  }
  // stage Y into S1 (P dead), coalesced store
  #pragma unroll
  for (int mt=0;mt<4;mt++)
    #pragma unroll
    for (int pt=0;pt<4;pt++)
      #pragma unroll
      for (int r=0;r<4;r++)
        S1[(mt*16+q*4+r)*72 + pt*16 + l15] = f2b(ya[mt][pt][r]);
  unsigned short* yb = d ? y1 : y0;
  for (int i=0;i<8;i++){
    int t = i*8 + tr; int g = ch*64 + t;
    int tph = d ? (LSEQ-1-g) : g;
    *(uint4*)(yb + ((size_t)b*LSEQ + tph)*DINNER + (size_t)h*64 + cb8) = *(uint4*)&S1[t*72 + cb8];
  }
  // BwT[n][s] = exp(L63-L_s)*B[s][n] into S2 (XdtT dead: fragments held in xf)
  float L63 = Lb[63];
  for (int i=0;i<8;i++){
    int s = i*8 + tr;
    float w = expf(L63 - Lb[s]);
    uint4 bv = *(const uint4*)(Bb + (tokb+s)*DSTATE + cb8);
    const unsigned short* bs = (const unsigned short*)&bv;
    #pragma unroll
    for (int j=0;j<8;j++){
      int jj = (j + c7) & 7;                 // bank-spread rotation
      S2[(cb8+jj)*72 + s] = f2b(w * b2f(bs[jj]));
    }
  }
  // GEMM3: G = XdtT . Bw  (A from regs, B from S2)
  f32x4 ga[4][4];
  for (int i=0;i<4;i++) for (int j=0;j<4;j++) ga[i][j] = (f32x4){0.f,0.f,0.f,0.f};
  #pragma unroll
  for (int ks=0; ks<2; ks++){
    short8 bw[4];
    #pragma unroll
    for (int nt=0;nt<4;nt++) bw[nt] = *(const short8*)(S2 + (nt*16+l15)*72 + ks*32 + q*8);
    #pragma unroll
    for (int mt=0;mt<4;mt++)
      #pragma unroll
      for (int nt=0;nt<4;nt++)
        ga[mt][nt] = __builtin_amdgcn_mfma_f32_16x16x32_bf16(xf[ks][mt], bw[nt], ga[mt][nt], 0,0,0);
  }
  #pragma unroll
  for (int pt=0;pt<4;pt++)
    #pragma unroll
    for (int nt=0;nt<4;nt++)
      #pragma unroll
      for (int r=0;r<4;r++)
        S1[(pt*16+q*4+r)*72 + nt*16 + l15] = f2b(ga[pt][nt][r]);
  for (int i=0;i<8;i++){
    int p = i*8 + tr;
    *(uint4*)(hbuf + zhc*4096 + (size_t)p*64 + cb8) = *(uint4*)&S1[p*72 + cb8];
  }
}

// ---------------- combine chunk states, IN PLACE ----------------
__global__ __launch_bounds__(256) void comb_k(unsigned short* __restrict__ hbuf,
    const float* __restrict__ Pch){
  int u = blockIdx.x; int tid = threadIdx.x;
  float hreg[16];
  #pragma unroll
  for (int k=0;k<16;k++) hreg[k]=0.f;
  for (int ch=0; ch<NCH; ch++){
    size_t base = ((size_t)u*NCH + ch)*4096;
    float P = Pch[(size_t)u*NCH + ch];
    #pragma unroll
    for (int k=0;k<16;k++){
      float t = b2f(hbuf[base + tid + k*256]);
      hbuf[base + tid + k*256] = f2b(hreg[k]);
      hreg[k] = hreg[k]*P + t;
    }
  }
}

// ---------------- SSD pass 2: Y += diag(e) C h_in^T + D*xh (2-slab version) ----------
__global__ __launch_bounds__(64) void ssd2_k(const unsigned short* __restrict__ Cb,
    const unsigned short* __restrict__ hbuf, const unsigned short* __restrict__ dtxb,
    const float* __restrict__ dtb, const float* __restrict__ ebuf, const float* __restrict__ Dh,
    unsigned short* __restrict__ y0, unsigned short* __restrict__ y1){
  int ch = blockIdx.x, h = blockIdx.y, z = blockIdx.z;
  int d = z >> 1, b = z & 1;
  int lane = threadIdx.x;
  int l15 = lane & 15, q = lane >> 4;
  int tr = lane >> 3, cb8 = (lane & 7)*8;
  size_t tokb = (size_t)z*LSEQ + (size_t)ch*64;
  size_t zhc = ((size_t)z*NHEADS + h)*NCH + ch;
  __shared__ __align__(16) unsigned short S1[64*72];
  __shared__ __align__(16) unsigned short S2[64*72];
  __shared__ float eb2[64], dti[64];
  eb2[lane] = ebuf[zhc*64 + lane];
  dti[lane] = 1.f / dtb[(tokb + lane)*NHEADS + h];
  float Dv = Dh[h];
  for (int i=0;i<8;i++){
    int t = i*8 + tr;
    *(uint4*)&S1[t*72 + cb8] = *(const uint4*)(Cb + (tokb+t)*DSTATE + cb8);
    *(uint4*)&S2[t*72 + cb8] = *(const uint4*)(hbuf + zhc*4096 + (size_t)t*64 + cb8);
  }
  f32x4 acc[4][4];
  for (int i=0;i<4;i++) for (int j=0;j<4;j++) acc[i][j] = (f32x4){0.f,0.f,0.f,0.f};
  gemm64(S1, S2, l15, q, acc);
  unsigned short* yb = d ? y1 : y0;
  // stage result into S1 (C dead after gemm; same-wave in-order DS)
  #pragma unroll
  for (int mt=0;mt<4;mt++){
    #pragma unroll
    for (int r=0;r<4;r++){
      int t = mt*16 + q*4 + r; int g = ch*64 + t;
      int tph = d ? (LSEQ-1-g) : g;
      size_t rowb = ((size_t)b*LSEQ + tph)*DINNER + (size_t)h*64;
      size_t dxb_ = (tokb + t)*DINNER + (size_t)h*64;
      float et = eb2[t], di = dti[t];
      #pragma unroll
      for (int pt=0;pt<4;pt++){
        int p = pt*16 + l15;
        float v = acc[mt][pt][r]*et + b2f(yb[rowb + p]) + Dv * b2f(dtxb[dxb_ + p]) * di;
        S1[t*72 + p] = f2b(v);
      }
    }
  }
  for (int i=0;i<8;i++){
    int t = i*8 + tr; int g = ch*64 + t;
    int tph = d ? (LSEQ-1-g) : g;
    *(uint4*)(yb + ((size_t)b*LSEQ + tph)*DINNER + (size_t)h*64 + cb8) = *(uint4*)&S1[t*72 + cb8];
  }
}

// ---------------- gate: g=y*silu(z), per-dir rmsnorm, sum, ->bf16 ----------------
__global__ __launch_bounds__(256) void gate_k(const unsigned short* __restrict__ y0,
    const unsigned short* __restrict__ y1, const unsigned short* __restrict__ zcomp,
    const float* __restrict__ mnw, unsigned short* __restrict__ gsum){
  int tok = blockIdx.x; int tid = threadIdx.x;
  __shared__ float g0s[DINNER], g1s[DINNER];
  float ss0 = 0.f, ss1 = 0.f;
  for (int i=0;i<4;i++){
    int c = tid + i*256;
    float z = b2f(zcomp[(size_t)tok*DINNER + c]);
    float sz = z / (1.f + expf(-z));
    float g0 = b2f(y0[(size_t)tok*DINNER + c]) * sz;
    float g1 = b2f(y1[(size_t)tok*DINNER + c]) * sz;
    g0s[c] = g0; g1s[c] = g1;
    ss0 += g0*g0; ss1 += g1*g1;
  }
  for (int m=32;m>=1;m>>=1){ ss0 += __shfl_xor(ss0,m); ss1 += __shfl_xor(ss1,m); }
  __shared__ float w0[4], w1[4];
  int wave = tid>>6, lane = tid&63;
  if (lane==0){ w0[wave]=ss0; w1[wave]=ss1; }
  __syncthreads();
  ss0 = w0[0]+w0[1]+w0[2]+w0[3];
  ss1 = w1[0]+w1[1]+w1[2]+w1[3];
  float r0 = rsqrtf(ss0*(1.f/DINNER) + 1e-5f);
  float r1 = rsqrtf(ss1*(1.f/DINNER) + 1e-5f);
  for (int i=0;i<4;i++){
    int c = tid + i*256;
    gsum[(size_t)tok*DINNER + c] = f2b((g0s[c]*r0 + g1s[c]*r1) * mnw[c]);
  }
}

extern "C" void kernel_launch(void* const* d_in, const int* in_sizes, int n_in,
                              void* d_out, int out_size, void* d_ws, size_t ws_size,
                              hipStream_t stream){
  const float* x       = (const float*)d_in[0];
  const float* nin_w   = (const float*)d_in[1];
  const float* nin_b   = (const float*)d_in[2];
  const float* nout_w  = (const float*)d_in[3];
  const float* nout_b  = (const float*)d_in[4];
  const float* in_w    = (const float*)d_in[5];
  const float* conv_w  = (const float*)d_in[6];
  const float* conv_b  = (const float*)d_in[7];
  const float* dt_bias = (const float*)d_in[8];
  const float* A_log   = (const float*)d_in[9];
  const float* D_h     = (const float*)d_in[10];
  const float* mnorm_w = (const float*)d_in[11];
  const float* out_w   = (const float*)d_in[12];
  const float* ff_w1   = (const float*)d_in[13];
  const float* ff_b1   = (const float*)d_in[14];
  const float* ff_w2   = (const float*)d_in[15];
  const float* ff_b2   = (const float*)d_in[16];
  float* out = (float*)d_out;

  char* ws = (char*)d_ws;
  size_t off = 0;
  auto alloc = [&](size_t bytes)->char*{
    char* p = ws + off; off = (off + bytes + 255) & ~(size_t)255; return p; };
  unsigned short* xn_bf = (unsigned short*)alloc((size_t)NTOK*DMODEL*2);
  unsigned short* in_wT = (unsigned short*)alloc((size_t)NPAD*DMODEL*2);
  unsigned short* out_wT= (unsigned short*)alloc((size_t)DMODEL*DINNER*2);
  unsigned short* w1T   = (unsigned short*)alloc((size_t)2048*DMODEL*2);
  unsigned short* w2T   = (unsigned short*)alloc((size_t)DMODEL*2048*2);
  unsigned short* zx    = (unsigned short*)alloc((size_t)NTOK*NPAD*2);      // 37.7 MB
  unsigned short* zcomp = (unsigned short*)alloc((size_t)NTOK*DINNER*2);    // 16.8 MB
  float*          dAb   = (float*)alloc((size_t)2*NTOK*NHEADS*4);
  float*          dtb   = (float*)alloc((size_t)2*NTOK*NHEADS*4);
  unsigned short* Bb    = (unsigned short*)alloc((size_t)2*NTOK*DSTATE*2);
  unsigned short* Cb    = (unsigned short*)alloc((size_t)2*NTOK*DSTATE*2);
  unsigned short* dtxb  = (unsigned short*)alloc((size_t)2*NTOK*DINNER*2);  // 33.6 MB
  unsigned short* y0    = (unsigned short*)alloc((size_t)NTOK*DINNER*2);    // 16.8 MB
  unsigned short* y1    = (unsigned short*)alloc((size_t)NTOK*DINNER*2);    // 16.8 MB
  float*          Pch   = (float*)alloc((size_t)64*NCH*4);
  float*          ebuf  = (float*)alloc((size_t)64*NCH*64*4);               // 1.05 MB
  size_t need = off;
  if (need > ws_size) return;  // fail absmax cleanly instead of faulting

  // aliases into sequentially-dead regions:
  unsigned short* hbuf  = zx;                          // chunk states; zx dead after conv kernels
  unsigned short* gsum  = dtxb;                        // dtxb dead after ssd2_k
  float* mpre = (float*)(dtxb + (size_t)NTOK*DINNER);  // 2nd half of dtxb
  unsigned short* m_bf  = y0;                          // y0 dead after gate_k
  unsigned short* h1    = zx;                          // hbuf dead after ssd2_k

  // weight transposes -> bf16 [N][K]
  wconv_t<<<dim3(NPAD/32,   DMODEL/32), 256, 0, stream>>>(in_w,  in_wT,  DMODEL, DPROJ,  NPAD);
  wconv_t<<<dim3(DMODEL/32, DINNER/32), 256, 0, stream>>>(out_w, out_wT, DINNER, DMODEL, DMODEL);
  wconv_t<<<dim3(2048/32,   DMODEL/32), 256, 0, stream>>>(ff_w1, w1T,    DMODEL, 2048,   2048);
  wconv_t<<<dim3(DMODEL/32, 2048/32),   256, 0, stream>>>(ff_w2, w2T,    2048,   DMODEL, DMODEL);
  // LN in -> bf16
  layernorm_k<<<NTOK, 256, 0, stream>>>(x, nin_w, nin_b, xn_bf);
  // in_proj (shared between directions) -> bf16 zx
  gemm_k<<<dim3(NPAD/128, NTOK/128), 256, 0, stream>>>(xn_bf, in_wT, zx, NTOK, NPAD, DMODEL, 3, nullptr, nullptr);
  // dt/dA then conv (both directions from one pass) + z compaction
  dt_k<<<dim3(LSEQ/16, BSZ), 256, 0, stream>>>(zx, dt_bias, A_log, dAb, dtb);
  conv_x_k<<<dim3(LSEQ/32, BSZ), 256, 0, stream>>>(zx, conv_w, conv_b, dtb, dtxb, zcomp);
  conv_bc_k<<<dim3(LSEQ/64, BSZ), 256, 0, stream>>>(zx, conv_w, conv_b, Bb, Cb);
  // chunked SSD: intra-chunk (MFMA) -> combine -> inter-chunk (MFMA)
  ssd1_k<<<dim3(NCH, NHEADS, 2*BSZ), 64, 0, stream>>>(dAb, dtxb, Bb, Cb, y0, y1, hbuf, Pch, ebuf);
  comb_k<<<64, 256, 0, stream>>>(hbuf, Pch);
  ssd2_k<<<dim3(NCH, NHEADS, 2*BSZ), 64, 0, stream>>>(Cb, hbuf, dtxb, dtb, ebuf, D_h, y0, y1);
  // gate + per-dir rmsnorm + sum (linearity: single out_proj GEMM)
  gate_k<<<NTOK, 256, 0, stream>>>(y0, y1, zcomp, mnorm_w, gsum);
  // out_proj -> f32 mpre
  gemm_k<<<dim3(DMODEL/128, NTOK/128), 256, 0, stream>>>(gsum, out_wT, mpre, NTOK, DMODEL, DINNER, 0, nullptr, nullptr);
  // LN out -> bf16
  layernorm_k<<<NTOK, 256, 0, stream>>>(mpre, nout_w, nout_b, m_bf);
  // ff1 + gelu -> bf16
  gemm_k<<<dim3(2048/128, NTOK/128), 256, 0, stream>>>(m_bf, w1T, h1, NTOK, 2048, DMODEL, 1, ff_b1, nullptr);
  // ff2 + bias + residual -> f32 out
  gemm_k<<<dim3(DMODEL/128, NTOK/128), 256, 0, stream>>>(h1, w2T, out, NTOK, DMODEL, 2048, 2, ff_b2, x);
}